// Round 1
// baseline (1011.356 us; speedup 1.0000x reference)
//
#include <hip/hip_runtime.h>
#include <hip/hip_bf16.h>
#include <math.h>

// Problem constants (from reference): N=50000, E=800000, IN=128, OUT=64, H1=2, H2=1
#define NNODES 50000
#define NEDGES 800000

// ---------- helpers ----------

// Order-preserving float<->uint encoding for atomicMax on floats.
// enc==0 is reserved: it decodes to -NaN, i.e. "no edge touched this slot"
// (matches the reference's isfinite(m) ? m : 0 guard).
__device__ __forceinline__ unsigned fenc(float f) {
    unsigned u = __float_as_uint(f);
    return (u & 0x80000000u) ? ~u : (u | 0x80000000u);
}
__device__ __forceinline__ float fdec(unsigned e) {
    unsigned u = (e & 0x80000000u) ? (e ^ 0x80000000u) : ~e;
    return __uint_as_float(u);
}

__device__ __forceinline__ float wave_sum(float v) {
#pragma unroll
    for (int off = 32; off > 0; off >>= 1) v += __shfl_down(v, off);
    return v;  // lane 0 holds the sum
}

// ---------- layer GEMMs (fp32 vector ALU; no fp32 MFMA on CDNA4) ----------

// h = feat(N,128) @ W(128,128); fused el/er = einsum('nhd,hd->nh')
// block = 256 threads = 2 nodes x 128 cols; each head's 64 cols = one wave.
__global__ __launch_bounds__(256) void gemm1_kernel(
    const float* __restrict__ feat, const float* __restrict__ W,
    const float* __restrict__ al, const float* __restrict__ ar,
    float* __restrict__ h, float* __restrict__ el, float* __restrict__ er) {
    __shared__ float sf[2][128];
    const int tid  = threadIdx.x;
    const int nib  = tid >> 7;        // node in block (0..1)
    const int col  = tid & 127;       // output column
    const int node = blockIdx.x * 2 + nib;
    sf[nib][col] = feat[node * 128 + col];
    __syncthreads();
    float acc = 0.f;
#pragma unroll 8
    for (int k = 0; k < 128; ++k)
        acc = fmaf(sf[nib][k], W[k * 128 + col], acc);
    h[node * 128 + col] = acc;
    const int head = col >> 6;
    const int lane = col & 63;
    float vl = wave_sum(acc * al[head * 64 + lane]);
    float vr = wave_sum(acc * ar[head * 64 + lane]);
    if (lane == 0) { el[node * 2 + head] = vl; er[node * 2 + head] = vr; }
}

// h2 = h1(N,128) @ W2(128,64); fused el2/er2 (H=1).
// block = 256 threads = 4 nodes x 64 cols; each node = one wave.
__global__ __launch_bounds__(256) void gemm2_kernel(
    const float* __restrict__ h1, const float* __restrict__ W,
    const float* __restrict__ al, const float* __restrict__ ar,
    float* __restrict__ h2, float* __restrict__ el, float* __restrict__ er) {
    __shared__ float sf[4][128];
    const int tid  = threadIdx.x;
    const int nib  = tid >> 6;        // node in block (0..3)
    const int lane = tid & 63;        // output column
    const int node = blockIdx.x * 4 + nib;
    sf[nib][lane]      = h1[node * 128 + lane];
    sf[nib][lane + 64] = h1[node * 128 + 64 + lane];
    __syncthreads();
    float acc = 0.f;
#pragma unroll 8
    for (int k = 0; k < 128; ++k)
        acc = fmaf(sf[nib][k], W[k * 64 + lane], acc);
    h2[node * 64 + lane] = acc;
    float vl = wave_sum(acc * al[lane]);
    float vr = wave_sum(acc * ar[lane]);
    if (lane == 0) { el[node] = vl; er[node] = vr; }
}

// ---------- edge-softmax 3-pass ----------

// pass 1: e = leaky_relu(el[src]+er[dst]); segment-max over dst via atomicMax
template <int H>
__global__ __launch_bounds__(256) void edge_lrelu_max(
    const int* __restrict__ src, const int* __restrict__ dst,
    const float* __restrict__ el, const float* __restrict__ er,
    float* __restrict__ ebuf, unsigned* __restrict__ menc) {
    int e = blockIdx.x * 256 + threadIdx.x;
    if (e >= NEDGES) return;
    int s = src[e], d = dst[e];
#pragma unroll
    for (int h = 0; h < H; ++h) {
        float v = el[s * H + h] + er[d * H + h];
        v = v > 0.f ? v : 0.2f * v;      // leaky_relu, slope 0.2
        ebuf[e * H + h] = v;
        atomicMax(&menc[d * H + h], fenc(v));
    }
}

// pass 2: ex = exp(e - m[dst]); segment-sum via atomicAdd
template <int H>
__global__ __launch_bounds__(256) void edge_exp_sum(
    const int* __restrict__ dst, const unsigned* __restrict__ menc,
    float* __restrict__ ebuf, float* __restrict__ ssum) {
    int e = blockIdx.x * 256 + threadIdx.x;
    if (e >= NEDGES) return;
    int d = dst[e];
#pragma unroll
    for (int h = 0; h < H; ++h) {
        unsigned enc = menc[d * H + h];
        float m = enc ? fdec(enc) : 0.f;   // enc==0 => isolated dst => m=0
        float ex = __expf(ebuf[e * H + h] - m);
        ebuf[e * H + h] = ex;
        atomicAdd(&ssum[d * H + h], ex);
    }
}

// pass 3: out[dst] += (ex/s[dst]) * hlin[src]; one wave per edge, lane = dim
template <int H>
__global__ __launch_bounds__(256) void edge_scatter(
    const int* __restrict__ src, const int* __restrict__ dst,
    const float* __restrict__ ebuf, const float* __restrict__ ssum,
    const float* __restrict__ hlin, float* __restrict__ outacc) {
    int w    = (blockIdx.x * 256 + threadIdx.x) >> 6;
    int lane = threadIdx.x & 63;
    if (w >= NEDGES) return;
    int s = src[w], d = dst[w];
#pragma unroll
    for (int h = 0; h < H; ++h) {
        float alpha = ebuf[w * H + h] / ssum[d * H + h];  // broadcast loads
        atomicAdd(&outacc[d * (H * 64) + h * 64 + lane],
                  alpha * hlin[s * (H * 64) + h * 64 + lane]);
    }
}

// ---------- elementwise ----------

// h1 = elu(out1 + b1), over N*128 elements
__global__ __launch_bounds__(256) void elu_bias_kernel(
    const float* __restrict__ acc, const float* __restrict__ b,
    float* __restrict__ out) {
    int i = blockIdx.x * 256 + threadIdx.x;
    float v = acc[i] + b[i & 127];
    out[i] = v > 0.f ? v : (__expf(v) - 1.f);
}

// out = ((h1[:,0,:]+h1[:,1,:])/2 + out2 + b2) * 0.5, over N*64 elements
__global__ __launch_bounds__(256) void final_kernel(
    const float* __restrict__ h1, const float* __restrict__ out2acc,
    const float* __restrict__ b2, float* __restrict__ out) {
    int i = blockIdx.x * 256 + threadIdx.x;
    int n = i >> 6, d = i & 63;
    float mean = (h1[n * 128 + d] + h1[n * 128 + 64 + d]) * 0.5f;
    out[i] = (mean + out2acc[i] + b2[d]) * 0.5f;
}

// ---------- launcher ----------

extern "C" void kernel_launch(void* const* d_in, const int* in_sizes, int n_in,
                              void* d_out, int out_size, void* d_ws, size_t ws_size,
                              hipStream_t stream) {
    const float* feat = (const float*)d_in[0];
    const int*   src  = (const int*)d_in[1];
    const int*   dst  = (const int*)d_in[2];
    const float* W1   = (const float*)d_in[3];
    const float* al1  = (const float*)d_in[4];
    const float* ar1  = (const float*)d_in[5];
    const float* b1   = (const float*)d_in[6];
    const float* W2   = (const float*)d_in[7];
    const float* al2  = (const float*)d_in[8];
    const float* ar2  = (const float*)d_in[9];
    const float* b2   = (const float*)d_in[10];
    float* out = (float*)d_out;
    float* w   = (float*)d_ws;

    // workspace layout (float offsets); total 22.2M floats = 88.8 MB
    const size_t oA    = 0;                      // h1_lin, later reused for h1=elu(...)
    const size_t oC    = oA    + (size_t)NNODES * 128;   // out1 accumulator
    const size_t oOut2 = oC    + (size_t)NNODES * 128;   // out2 accumulator
    const size_t oM1   = oOut2 + (size_t)NNODES * 64;    // m1 enc (uint), N*2
    const size_t oS1   = oM1   + (size_t)NNODES * 2;     // s1, N*2
    const size_t oM2   = oS1   + (size_t)NNODES * 2;     // m2 enc, N
    const size_t oS2   = oM2   + (size_t)NNODES;         // s2, N
    const size_t oEl1  = oS2   + (size_t)NNODES;         // el1, N*2
    const size_t oEr1  = oEl1  + (size_t)NNODES * 2;     // er1, N*2
    const size_t oE1   = oEr1  + (size_t)NNODES * 2;     // edge buf layer1, E*2
    const size_t oH2   = oE1   + (size_t)NEDGES * 2;     // h2_lin, N*64
    const size_t oEl2  = oH2   + (size_t)NNODES * 64;    // el2, N
    const size_t oEr2  = oEl2  + (size_t)NNODES;         // er2, N
    const size_t oE2   = oEr2  + (size_t)NNODES;         // edge buf layer2, E

    // zero all accumulators in one shot: [oC .. oS2+N) is contiguous
    const size_t zeroFloats = (oS2 + (size_t)NNODES) - oC;
    hipMemsetAsync(w + oC, 0, zeroFloats * sizeof(float), stream);

    // ---- layer 1 ----
    gemm1_kernel<<<NNODES / 2, 256, 0, stream>>>(feat, W1, al1, ar1,
                                                 w + oA, w + oEl1, w + oEr1);
    edge_lrelu_max<2><<<(NEDGES + 255) / 256, 256, 0, stream>>>(
        src, dst, w + oEl1, w + oEr1, w + oE1, (unsigned*)(w + oM1));
    edge_exp_sum<2><<<(NEDGES + 255) / 256, 256, 0, stream>>>(
        dst, (const unsigned*)(w + oM1), w + oE1, w + oS1);
    edge_scatter<2><<<NEDGES / 4, 256, 0, stream>>>(
        src, dst, w + oE1, w + oS1, w + oA, w + oC);
    elu_bias_kernel<<<NNODES * 128 / 256, 256, 0, stream>>>(w + oC, b1, w + oA);

    // ---- layer 2 ----
    gemm2_kernel<<<NNODES / 4, 256, 0, stream>>>(w + oA, W2, al2, ar2,
                                                 w + oH2, w + oEl2, w + oEr2);
    edge_lrelu_max<1><<<(NEDGES + 255) / 256, 256, 0, stream>>>(
        src, dst, w + oEl2, w + oEr2, w + oE2, (unsigned*)(w + oM2));
    edge_exp_sum<1><<<(NEDGES + 255) / 256, 256, 0, stream>>>(
        dst, (const unsigned*)(w + oM2), w + oE2, w + oS2);
    edge_scatter<1><<<NEDGES / 4, 256, 0, stream>>>(
        src, dst, w + oE2, w + oS2, w + oH2, w + oOut2);

    // ---- combine ----
    final_kernel<<<NNODES * 64 / 256, 256, 0, stream>>>(w + oA, w + oOut2, b2, out);
}

// Round 2
// 501.468 us; speedup vs baseline: 2.0168x; 2.0168x over previous
//
#include <hip/hip_runtime.h>
#include <math.h>

// Problem constants: N=50000, E=800000, IN=128, OUT=64, H1=2, H2=1
#define NNODES 50000
#define NEDGES 800000
#define NCHUNK ((NNODES + 255) / 256)   // 196

// ---------------- CSR build (by dst; shared by both layers) ----------------

__global__ __launch_bounds__(256) void hist_kernel(const int* __restrict__ dst,
                                                   int* __restrict__ deg) {
    int e = blockIdx.x * 256 + threadIdx.x;
    if (e < NEDGES) atomicAdd(&deg[dst[e]], 1);
}

// per-256-chunk sums
__global__ __launch_bounds__(256) void scanA_kernel(const int* __restrict__ deg,
                                                    int* __restrict__ bsum) {
    __shared__ int s[256];
    int i = blockIdx.x * 256 + threadIdx.x;
    s[threadIdx.x] = (i < NNODES) ? deg[i] : 0;
    __syncthreads();
    for (int off = 128; off > 0; off >>= 1) {
        if (threadIdx.x < off) s[threadIdx.x] += s[threadIdx.x + off];
        __syncthreads();
    }
    if (threadIdx.x == 0) bsum[blockIdx.x] = s[0];
}

// exclusive scan of the NCHUNK partials, single wave
__global__ __launch_bounds__(64) void scanB_kernel(int* __restrict__ bsum) {
    int lane = threadIdx.x;
    int carry = 0;
    for (int base = 0; base < NCHUNK; base += 64) {
        int idx = base + lane;
        int v = (idx < NCHUNK) ? bsum[idx] : 0;
        int incl = v;
#pragma unroll
        for (int off = 1; off < 64; off <<= 1) {
            int t = __shfl_up(incl, off);
            if (lane >= off) incl += t;
        }
        if (idx < NCHUNK) bsum[idx] = carry + incl - v;  // exclusive
        carry += __shfl(incl, 63);
    }
}

// per-chunk exclusive scan + chunk offset -> rowptr and cursor
__global__ __launch_bounds__(256) void scanC_kernel(const int* __restrict__ deg,
                                                    const int* __restrict__ bsum,
                                                    int* __restrict__ rowptr,
                                                    int* __restrict__ cursor) {
    __shared__ int s[256];
    int i = blockIdx.x * 256 + threadIdx.x;
    int v = (i < NNODES) ? deg[i] : 0;
    s[threadIdx.x] = v;
    __syncthreads();
    for (int off = 1; off < 256; off <<= 1) {
        int t = (threadIdx.x >= off) ? s[threadIdx.x - off] : 0;
        __syncthreads();
        s[threadIdx.x] += t;
        __syncthreads();
    }
    if (i < NNODES) {
        int excl = bsum[blockIdx.x] + s[threadIdx.x] - v;
        rowptr[i] = excl;
        cursor[i] = excl;
    }
}

__global__ __launch_bounds__(256) void fill_kernel(const int* __restrict__ src,
                                                   const int* __restrict__ dst,
                                                   int* __restrict__ cursor,
                                                   int* __restrict__ csr_src) {
    int e = blockIdx.x * 256 + threadIdx.x;
    if (e < NEDGES) {
        int pos = atomicAdd(&cursor[dst[e]], 1);
        csr_src[pos] = src[e];
    }
}

// ---------------- GEMMs (fp32 vector ALU; no fp32 MFMA on CDNA4) -----------

__device__ __forceinline__ float wave_sum(float v) {
#pragma unroll
    for (int off = 32; off > 0; off >>= 1) v += __shfl_down(v, off);
    return v;
}

// h = feat(N,128) @ W(128,128); fused el/er. 256 thr = 2 nodes x 128 cols.
__global__ __launch_bounds__(256) void gemm1_kernel(
    const float* __restrict__ feat, const float* __restrict__ W,
    const float* __restrict__ al, const float* __restrict__ ar,
    float* __restrict__ h, float* __restrict__ el, float* __restrict__ er) {
    __shared__ float sf[2][128];
    const int tid  = threadIdx.x;
    const int nib  = tid >> 7;
    const int col  = tid & 127;
    const int node = blockIdx.x * 2 + nib;
    sf[nib][col] = feat[(size_t)node * 128 + col];
    __syncthreads();
    float acc = 0.f;
#pragma unroll 8
    for (int k = 0; k < 128; ++k)
        acc = fmaf(sf[nib][k], W[k * 128 + col], acc);
    h[(size_t)node * 128 + col] = acc;
    const int head = col >> 6;
    const int lane = col & 63;
    float vl = wave_sum(acc * al[head * 64 + lane]);
    float vr = wave_sum(acc * ar[head * 64 + lane]);
    if (lane == 0) { el[node * 2 + head] = vl; er[node * 2 + head] = vr; }
}

// h2 = h1(N,128) @ W2(128,64); fused el2/er2. 256 thr = 4 nodes x 64 cols.
__global__ __launch_bounds__(256) void gemm2_kernel(
    const float* __restrict__ h1, const float* __restrict__ W,
    const float* __restrict__ al, const float* __restrict__ ar,
    float* __restrict__ h2, float* __restrict__ el, float* __restrict__ er) {
    __shared__ float sf[4][128];
    const int tid  = threadIdx.x;
    const int nib  = tid >> 6;
    const int lane = tid & 63;
    const int node = blockIdx.x * 4 + nib;
    sf[nib][lane]      = h1[(size_t)node * 128 + lane];
    sf[nib][lane + 64] = h1[(size_t)node * 128 + 64 + lane];
    __syncthreads();
    float acc = 0.f;
#pragma unroll 8
    for (int k = 0; k < 128; ++k)
        acc = fmaf(sf[nib][k], W[k * 64 + lane], acc);
    h2[(size_t)node * 64 + lane] = acc;
    float vl = wave_sum(acc * al[lane]);
    float vr = wave_sum(acc * ar[lane]);
    if (lane == 0) { el[node] = vl; er[node] = vr; }
}

// --------- fused edge-softmax + gather-aggregate: one wave per (dst,head) --

template <int H, bool LAYER1>
__global__ __launch_bounds__(256) void aggregate_kernel(
    const int* __restrict__ rowptr, const int* __restrict__ degv,
    const int* __restrict__ csr_src,
    const float* __restrict__ el, const float* __restrict__ er,
    const float* __restrict__ hlin,
    const float* __restrict__ bias,
    const float* __restrict__ h1,    // layer2 only: for the h1-mean term
    float* __restrict__ outp) {
    const int wid  = (blockIdx.x * 256 + threadIdx.x) >> 6;
    const int lane = threadIdx.x & 63;
    const int node = (H == 2) ? (wid >> 1) : wid;
    const int head = (H == 2) ? (wid & 1) : 0;
    if (node >= NNODES) return;
    const int row = rowptr[node];
    const int deg = degv[node];
    const float erd = er[node * H + head];

    // lane i caches edge i's src and leaky_relu(e) in registers (deg<=64 case)
    int   s_reg = 0;
    float v_reg = -1e30f;
    if (lane < deg) {
        s_reg = csr_src[row + lane];
        float v = el[s_reg * H + head] + erd;
        v_reg = v > 0.f ? v : 0.2f * v;
    }
    float m = v_reg;
    for (int i = 64 + lane; i < deg; i += 64) {         // rare tail (deg>64)
        int s = csr_src[row + i];
        float v = el[s * H + head] + erd;
        v = v > 0.f ? v : 0.2f * v;
        m = fmaxf(m, v);
    }
#pragma unroll
    for (int off = 32; off > 0; off >>= 1) m = fmaxf(m, __shfl_xor(m, off));

    float p_reg = (lane < deg) ? __expf(v_reg - m) : 0.f;
    float ssum = p_reg;
    for (int i = 64 + lane; i < deg; i += 64) {
        int s = csr_src[row + i];
        float v = el[s * H + head] + erd;
        v = v > 0.f ? v : 0.2f * v;
        ssum += __expf(v - m);
    }
#pragma unroll
    for (int off = 32; off > 0; off >>= 1) ssum += __shfl_xor(ssum, off);

    float acc = 0.f;
    const int dmax = deg < 64 ? deg : 64;
    for (int i = 0; i < dmax; ++i) {
        int   s = __shfl(s_reg, i);
        float p = __shfl(p_reg, i);
        acc = fmaf(p, hlin[(size_t)s * (H * 64) + head * 64 + lane], acc);
    }
    for (int i = 64; i < deg; ++i) {                    // rare tail
        int s = csr_src[row + i];                       // broadcast load
        float v = el[s * H + head] + erd;
        v = v > 0.f ? v : 0.2f * v;
        acc = fmaf(__expf(v - m), hlin[(size_t)s * (H * 64) + head * 64 + lane], acc);
    }
    if (deg > 0) acc /= ssum;                           // deg==0 -> acc=0 (ref guard)

    if (LAYER1) {
        float o = acc + bias[head * 64 + lane];
        outp[(size_t)node * 128 + head * 64 + lane] = o > 0.f ? o : (__expf(o) - 1.f);
    } else {
        float mean = (h1[(size_t)node * 128 + lane] + h1[(size_t)node * 128 + 64 + lane]) * 0.5f;
        outp[(size_t)node * 64 + lane] = (mean + acc + bias[lane]) * 0.5f;
    }
}

// ---------------- launcher ----------------

extern "C" void kernel_launch(void* const* d_in, const int* in_sizes, int n_in,
                              void* d_out, int out_size, void* d_ws, size_t ws_size,
                              hipStream_t stream) {
    const float* feat = (const float*)d_in[0];
    const int*   src  = (const int*)d_in[1];
    const int*   dst  = (const int*)d_in[2];
    const float* W1   = (const float*)d_in[3];
    const float* al1  = (const float*)d_in[4];
    const float* ar1  = (const float*)d_in[5];
    const float* b1   = (const float*)d_in[6];
    const float* W2   = (const float*)d_in[7];
    const float* al2  = (const float*)d_in[8];
    const float* ar2  = (const float*)d_in[9];
    const float* b2   = (const float*)d_in[10];
    float* out = (float*)d_out;

    // workspace layout, 4-byte units (~17.3M elems = 69 MB)
    int*   ideg   = (int*)d_ws;                         // N
    int*   irow   = ideg + NNODES;                      // N
    int*   icur   = irow + NNODES;                      // N
    int*   ibsum  = icur + NNODES;                      // 256
    int*   icsr   = ibsum + 256;                        // E
    float* fH1L   = (float*)(icsr + NEDGES);            // N*128 (h1 linear)
    float* fH1    = fH1L + (size_t)NNODES * 128;        // N*128 (post elu)
    float* fEl1   = fH1  + (size_t)NNODES * 128;        // N*2
    float* fEr1   = fEl1 + (size_t)NNODES * 2;          // N*2
    float* fH2L   = fEr1 + (size_t)NNODES * 2;          // N*64
    float* fEl2   = fH2L + (size_t)NNODES * 64;         // N
    float* fEr2   = fEl2 + (size_t)NNODES;              // N

    // ---- CSR build (once; both layers share the graph) ----
    hipMemsetAsync(ideg, 0, NNODES * sizeof(int), stream);
    hist_kernel<<<(NEDGES + 255) / 256, 256, 0, stream>>>(dst, ideg);
    scanA_kernel<<<NCHUNK, 256, 0, stream>>>(ideg, ibsum);
    scanB_kernel<<<1, 64, 0, stream>>>(ibsum);
    scanC_kernel<<<NCHUNK, 256, 0, stream>>>(ideg, ibsum, irow, icur);
    fill_kernel<<<(NEDGES + 255) / 256, 256, 0, stream>>>(src, dst, icur, icsr);

    // ---- layer 1 ----
    gemm1_kernel<<<NNODES / 2, 256, 0, stream>>>(feat, W1, al1, ar1,
                                                 fH1L, fEl1, fEr1);
    aggregate_kernel<2, true><<<(NNODES * 2 + 3) / 4, 256, 0, stream>>>(
        irow, ideg, icsr, fEl1, fEr1, fH1L, b1, nullptr, fH1);

    // ---- layer 2 ----
    gemm2_kernel<<<NNODES / 4, 256, 0, stream>>>(fH1, W2, al2, ar2,
                                                 fH2L, fEl2, fEr2);
    aggregate_kernel<1, false><<<(NNODES + 3) / 4, 256, 0, stream>>>(
        irow, ideg, icsr, fEl2, fEr2, fH2L, b2, fH1, out);
}

// Round 3
// 404.735 us; speedup vs baseline: 2.4988x; 1.2390x over previous
//
#include <hip/hip_runtime.h>
#include <math.h>

// Problem constants: N=50000, E=800000, IN=128, OUT=64, H1=2, H2=1
#define NNODES 50000
#define NEDGES 800000
#define NCHUNK ((NNODES + 255) / 256)   // 196

// ---------------- CSR build (by dst; shared by both layers) ----------------

__global__ __launch_bounds__(256) void hist_kernel(const int* __restrict__ dst,
                                                   int* __restrict__ deg) {
    int e = blockIdx.x * 256 + threadIdx.x;
    if (e < NEDGES) atomicAdd(&deg[dst[e]], 1);
}

__global__ __launch_bounds__(256) void scanA_kernel(const int* __restrict__ deg,
                                                    int* __restrict__ bsum) {
    __shared__ int s[256];
    int i = blockIdx.x * 256 + threadIdx.x;
    s[threadIdx.x] = (i < NNODES) ? deg[i] : 0;
    __syncthreads();
    for (int off = 128; off > 0; off >>= 1) {
        if (threadIdx.x < off) s[threadIdx.x] += s[threadIdx.x + off];
        __syncthreads();
    }
    if (threadIdx.x == 0) bsum[blockIdx.x] = s[0];
}

__global__ __launch_bounds__(64) void scanB_kernel(int* __restrict__ bsum) {
    int lane = threadIdx.x;
    int carry = 0;
    for (int base = 0; base < NCHUNK; base += 64) {
        int idx = base + lane;
        int v = (idx < NCHUNK) ? bsum[idx] : 0;
        int incl = v;
#pragma unroll
        for (int off = 1; off < 64; off <<= 1) {
            int t = __shfl_up(incl, off);
            if (lane >= off) incl += t;
        }
        if (idx < NCHUNK) bsum[idx] = carry + incl - v;  // exclusive
        carry += __shfl(incl, 63);
    }
}

__global__ __launch_bounds__(256) void scanC_kernel(const int* __restrict__ deg,
                                                    const int* __restrict__ bsum,
                                                    int* __restrict__ rowptr,
                                                    int* __restrict__ cursor) {
    __shared__ int s[256];
    int i = blockIdx.x * 256 + threadIdx.x;
    int v = (i < NNODES) ? deg[i] : 0;
    s[threadIdx.x] = v;
    __syncthreads();
    for (int off = 1; off < 256; off <<= 1) {
        int t = (threadIdx.x >= off) ? s[threadIdx.x - off] : 0;
        __syncthreads();
        s[threadIdx.x] += t;
        __syncthreads();
    }
    if (i < NNODES) {
        int excl = bsum[blockIdx.x] + s[threadIdx.x] - v;
        rowptr[i] = excl;
        cursor[i] = excl;
    }
}

__global__ __launch_bounds__(256) void fill_kernel(const int* __restrict__ src,
                                                   const int* __restrict__ dst,
                                                   int* __restrict__ cursor,
                                                   int* __restrict__ csr_src) {
    int e = blockIdx.x * 256 + threadIdx.x;
    if (e < NEDGES) {
        int pos = atomicAdd(&cursor[dst[e]], 1);
        csr_src[pos] = src[e];
    }
}

// ---------------- GEMMs: LDS-tiled, register-blocked fp32 -----------------
// No fp32 MFMA on CDNA4 -> vector ALU; goal is FMA-issue-bound, not latency.

// gemm1: h(N,128) = feat(N,128) @ W1(128,128), fused el/er.
// BM=64, BN=128, BK=32; 256 thr = 16 tx (cols) x 16 ty (nodes); 4x8 per thread.
// Thread's 8 cols = {tx*4..+3} in head0 and {64+tx*4..+3} in head1 -> W-tile
// reads have bank stride 4 (2-way alias = free) and el/er for BOTH heads
// reduce over the same 16 tx lanes.
__global__ __launch_bounds__(256) void gemm1_kernel(
    const float* __restrict__ feat, const float* __restrict__ W,
    const float* __restrict__ al, const float* __restrict__ ar,
    float* __restrict__ h, float* __restrict__ el, float* __restrict__ er) {
    __shared__ float As[64][36];      // [node][k], pad 36: A-reads 2-way (free)
    __shared__ float Ws[32 * 128];    // [k][col], linear copy of W rows
    const int tid = threadIdx.x;
    const int tx  = tid & 15;
    const int ty  = tid >> 4;
    const int n0  = blockIdx.x * 64;

    float acc[4][8];
#pragma unroll
    for (int i = 0; i < 4; ++i)
#pragma unroll
        for (int j = 0; j < 8; ++j) acc[i][j] = 0.f;

    for (int k0 = 0; k0 < 128; k0 += 32) {
        // stage A tile (64 nodes x 32 k): 2 float4 per thread, coalesced
#pragma unroll
        for (int i = 0; i < 2; ++i) {
            int fid = i * 256 + tid;            // 0..511
            int n = fid >> 3, j = fid & 7;
            float4 v = make_float4(0.f, 0.f, 0.f, 0.f);
            if (n0 + n < NNODES)
                v = *(const float4*)&feat[(size_t)(n0 + n) * 128 + k0 + 4 * j];
            *(float4*)&As[n][4 * j] = v;
        }
        // stage W tile (32 k x 128 cols): linear copy, 4 float4 per thread
#pragma unroll
        for (int i = 0; i < 4; ++i) {
            int fid = i * 256 + tid;            // float4 id 0..1023
            *(float4*)&Ws[fid * 4] = *(const float4*)&W[k0 * 128 + fid * 4];
        }
        __syncthreads();
#pragma unroll
        for (int k = 0; k < 32; ++k) {
            float a0 = As[ty * 4 + 0][k];
            float a1 = As[ty * 4 + 1][k];
            float a2 = As[ty * 4 + 2][k];
            float a3 = As[ty * 4 + 3][k];
            float4 w0 = *(const float4*)&Ws[k * 128 + tx * 4];
            float4 w1 = *(const float4*)&Ws[k * 128 + 64 + tx * 4];
            float wv[8] = {w0.x, w0.y, w0.z, w0.w, w1.x, w1.y, w1.z, w1.w};
#pragma unroll
            for (int j = 0; j < 8; ++j) {
                acc[0][j] = fmaf(a0, wv[j], acc[0][j]);
                acc[1][j] = fmaf(a1, wv[j], acc[1][j]);
                acc[2][j] = fmaf(a2, wv[j], acc[2][j]);
                acc[3][j] = fmaf(a3, wv[j], acc[3][j]);
            }
        }
        __syncthreads();
    }

    // attn vectors for this thread's cols (same for all 4 nodes)
    float alv[8], arv[8];
#pragma unroll
    for (int j = 0; j < 4; ++j) {
        alv[j]     = al[tx * 4 + j];        arv[j]     = ar[tx * 4 + j];
        alv[4 + j] = al[64 + tx * 4 + j];   arv[4 + j] = ar[64 + tx * 4 + j];
    }

#pragma unroll
    for (int i = 0; i < 4; ++i) {
        const int node = n0 + ty * 4 + i;
        if (node < NNODES) {
            float4 o0 = {acc[i][0], acc[i][1], acc[i][2], acc[i][3]};
            float4 o1 = {acc[i][4], acc[i][5], acc[i][6], acc[i][7]};
            *(float4*)&h[(size_t)node * 128 + tx * 4]      = o0;
            *(float4*)&h[(size_t)node * 128 + 64 + tx * 4] = o1;
        }
        float vl0 = 0.f, vr0 = 0.f, vl1 = 0.f, vr1 = 0.f;
#pragma unroll
        for (int j = 0; j < 4; ++j) {
            vl0 = fmaf(acc[i][j], alv[j], vl0);
            vr0 = fmaf(acc[i][j], arv[j], vr0);
            vl1 = fmaf(acc[i][4 + j], alv[4 + j], vl1);
            vr1 = fmaf(acc[i][4 + j], arv[4 + j], vr1);
        }
#pragma unroll
        for (int m = 1; m <= 8; m <<= 1) {   // reduce over 16 tx lanes
            vl0 += __shfl_xor(vl0, m); vr0 += __shfl_xor(vr0, m);
            vl1 += __shfl_xor(vl1, m); vr1 += __shfl_xor(vr1, m);
        }
        if (tx == 0 && node < NNODES) {
            el[node * 2 + 0] = vl0;  er[node * 2 + 0] = vr0;
            el[node * 2 + 1] = vl1;  er[node * 2 + 1] = vr1;
        }
    }
}

// gemm2: h2(N,64) = h1(N,128) @ W2(128,64), fused el2/er2 (H=1).
// BM=128, BN=64, BK=32; 256 thr = 16 tx (cols, 4 each) x 16 ty (nodes, 8 each).
__global__ __launch_bounds__(256) void gemm2_kernel(
    const float* __restrict__ h1, const float* __restrict__ W,
    const float* __restrict__ al, const float* __restrict__ ar,
    float* __restrict__ h2, float* __restrict__ el, float* __restrict__ er) {
    __shared__ float As[128][34];     // pad 34: A-reads 2-way (free)
    __shared__ float Ws[32 * 64];
    const int tid = threadIdx.x;
    const int tx  = tid & 15;
    const int ty  = tid >> 4;
    const int n0  = blockIdx.x * 128;

    float acc[8][4];
#pragma unroll
    for (int i = 0; i < 8; ++i)
#pragma unroll
        for (int j = 0; j < 4; ++j) acc[i][j] = 0.f;

    for (int k0 = 0; k0 < 128; k0 += 32) {
        // stage A tile (128 x 32): 4 float4-loads per thread, float2 stores
        // (row pad 34 keeps 8B alignment; float4 would be misaligned)
#pragma unroll
        for (int i = 0; i < 4; ++i) {
            int fid = i * 256 + tid;            // 0..1023
            int n = fid >> 3, j = fid & 7;
            float4 v = make_float4(0.f, 0.f, 0.f, 0.f);
            if (n0 + n < NNODES)
                v = *(const float4*)&h1[(size_t)(n0 + n) * 128 + k0 + 4 * j];
            *(float2*)&As[n][4 * j]     = make_float2(v.x, v.y);
            *(float2*)&As[n][4 * j + 2] = make_float2(v.z, v.w);
        }
        // stage W tile (32 x 64): linear copy, 2 float4 per thread
#pragma unroll
        for (int i = 0; i < 2; ++i) {
            int fid = i * 256 + tid;            // float4 id 0..511
            *(float4*)&Ws[fid * 4] = *(const float4*)&W[k0 * 64 + fid * 4];
        }
        __syncthreads();
#pragma unroll
        for (int k = 0; k < 32; ++k) {
            float4 w = *(const float4*)&Ws[k * 64 + tx * 4];
            float wv[4] = {w.x, w.y, w.z, w.w};
#pragma unroll
            for (int i = 0; i < 8; ++i) {
                float a = As[ty * 8 + i][k];
#pragma unroll
                for (int j = 0; j < 4; ++j)
                    acc[i][j] = fmaf(a, wv[j], acc[i][j]);
            }
        }
        __syncthreads();
    }

    float alv[4], arv[4];
#pragma unroll
    for (int j = 0; j < 4; ++j) { alv[j] = al[tx * 4 + j]; arv[j] = ar[tx * 4 + j]; }

#pragma unroll
    for (int i = 0; i < 8; ++i) {
        const int node = n0 + ty * 8 + i;
        if (node < NNODES) {
            float4 o = {acc[i][0], acc[i][1], acc[i][2], acc[i][3]};
            *(float4*)&h2[(size_t)node * 64 + tx * 4] = o;
        }
        float vl = 0.f, vr = 0.f;
#pragma unroll
        for (int j = 0; j < 4; ++j) {
            vl = fmaf(acc[i][j], alv[j], vl);
            vr = fmaf(acc[i][j], arv[j], vr);
        }
#pragma unroll
        for (int m = 1; m <= 8; m <<= 1) {
            vl += __shfl_xor(vl, m); vr += __shfl_xor(vr, m);
        }
        if (tx == 0 && node < NNODES) { el[node] = vl; er[node] = vr; }
    }
}

// --------- fused edge-softmax + gather-aggregate: one wave per (dst,head) --

template <int H, bool LAYER1>
__global__ __launch_bounds__(256) void aggregate_kernel(
    const int* __restrict__ rowptr, const int* __restrict__ degv,
    const int* __restrict__ csr_src,
    const float* __restrict__ el, const float* __restrict__ er,
    const float* __restrict__ hlin,
    const float* __restrict__ bias,
    const float* __restrict__ h1,    // layer2 only: h1-mean term
    float* __restrict__ outp) {
    const int wid  = (blockIdx.x * 256 + threadIdx.x) >> 6;
    const int lane = threadIdx.x & 63;
    const int node = (H == 2) ? (wid >> 1) : wid;
    const int head = (H == 2) ? (wid & 1) : 0;
    if (node >= NNODES) return;
    const int row = rowptr[node];
    const int deg = degv[node];
    const float erd = er[node * H + head];

    int   s_reg = 0;
    float v_reg = -1e30f;
    if (lane < deg) {
        s_reg = csr_src[row + lane];
        float v = el[s_reg * H + head] + erd;
        v_reg = v > 0.f ? v : 0.2f * v;
    }
    float m = v_reg;
    for (int i = 64 + lane; i < deg; i += 64) {
        int s = csr_src[row + i];
        float v = el[s * H + head] + erd;
        v = v > 0.f ? v : 0.2f * v;
        m = fmaxf(m, v);
    }
#pragma unroll
    for (int off = 32; off > 0; off >>= 1) m = fmaxf(m, __shfl_xor(m, off));

    float p_reg = (lane < deg) ? __expf(v_reg - m) : 0.f;
    float ssum = p_reg;
    for (int i = 64 + lane; i < deg; i += 64) {
        int s = csr_src[row + i];
        float v = el[s * H + head] + erd;
        v = v > 0.f ? v : 0.2f * v;
        ssum += __expf(v - m);
    }
#pragma unroll
    for (int off = 32; off > 0; off >>= 1) ssum += __shfl_xor(ssum, off);

    float acc = 0.f;
    const int dmax = deg < 64 ? deg : 64;
    for (int i = 0; i < dmax; ++i) {
        int   s = __shfl(s_reg, i);
        float p = __shfl(p_reg, i);
        acc = fmaf(p, hlin[(size_t)s * (H * 64) + head * 64 + lane], acc);
    }
    for (int i = 64; i < deg; ++i) {
        int s = csr_src[row + i];
        float v = el[s * H + head] + erd;
        v = v > 0.f ? v : 0.2f * v;
        acc = fmaf(__expf(v - m), hlin[(size_t)s * (H * 64) + head * 64 + lane], acc);
    }
    if (deg > 0) acc /= ssum;

    if (LAYER1) {
        float o = acc + bias[head * 64 + lane];
        outp[(size_t)node * 128 + head * 64 + lane] = o > 0.f ? o : (__expf(o) - 1.f);
    } else {
        float mean = (h1[(size_t)node * 128 + lane] + h1[(size_t)node * 128 + 64 + lane]) * 0.5f;
        outp[(size_t)node * 64 + lane] = (mean + acc + bias[lane]) * 0.5f;
    }
}

// ---------------- launcher ----------------

extern "C" void kernel_launch(void* const* d_in, const int* in_sizes, int n_in,
                              void* d_out, int out_size, void* d_ws, size_t ws_size,
                              hipStream_t stream) {
    const float* feat = (const float*)d_in[0];
    const int*   src  = (const int*)d_in[1];
    const int*   dst  = (const int*)d_in[2];
    const float* W1   = (const float*)d_in[3];
    const float* al1  = (const float*)d_in[4];
    const float* ar1  = (const float*)d_in[5];
    const float* b1   = (const float*)d_in[6];
    const float* W2   = (const float*)d_in[7];
    const float* al2  = (const float*)d_in[8];
    const float* ar2  = (const float*)d_in[9];
    const float* b2   = (const float*)d_in[10];
    float* out = (float*)d_out;

    int*   ideg   = (int*)d_ws;                         // N
    int*   irow   = ideg + NNODES;                      // N
    int*   icur   = irow + NNODES;                      // N
    int*   ibsum  = icur + NNODES;                      // 256
    int*   icsr   = ibsum + 256;                        // E
    float* fH1L   = (float*)(icsr + NEDGES);            // N*128
    float* fH1    = fH1L + (size_t)NNODES * 128;        // N*128
    float* fEl1   = fH1  + (size_t)NNODES * 128;        // N*2
    float* fEr1   = fEl1 + (size_t)NNODES * 2;          // N*2
    float* fH2L   = fEr1 + (size_t)NNODES * 2;          // N*64
    float* fEl2   = fH2L + (size_t)NNODES * 64;         // N
    float* fEr2   = fEl2 + (size_t)NNODES;              // N

    // ---- CSR build (once; both layers share the graph) ----
    hipMemsetAsync(ideg, 0, NNODES * sizeof(int), stream);
    hist_kernel<<<(NEDGES + 255) / 256, 256, 0, stream>>>(dst, ideg);
    scanA_kernel<<<NCHUNK, 256, 0, stream>>>(ideg, ibsum);
    scanB_kernel<<<1, 64, 0, stream>>>(ibsum);
    scanC_kernel<<<NCHUNK, 256, 0, stream>>>(ideg, ibsum, irow, icur);
    fill_kernel<<<(NEDGES + 255) / 256, 256, 0, stream>>>(src, dst, icur, icsr);

    // ---- layer 1 ----
    gemm1_kernel<<<(NNODES + 63) / 64, 256, 0, stream>>>(feat, W1, al1, ar1,
                                                         fH1L, fEl1, fEr1);
    aggregate_kernel<2, true><<<(NNODES * 2 + 3) / 4, 256, 0, stream>>>(
        irow, ideg, icsr, fEl1, fEr1, fH1L, b1, nullptr, fH1);

    // ---- layer 2 ----
    gemm2_kernel<<<(NNODES + 127) / 128, 256, 0, stream>>>(fH1, W2, al2, ar2,
                                                           fH2L, fEl2, fEr2);
    aggregate_kernel<1, false><<<(NNODES + 3) / 4, 256, 0, stream>>>(
        irow, ideg, icsr, fEl2, fEr2, fH2L, b2, fH1, out);
}

// Round 6
// 360.031 us; speedup vs baseline: 2.8091x; 1.1242x over previous
//
#include <hip/hip_runtime.h>
#include <math.h>

// Problem constants: N=50000, E=800000, IN=128, OUT=64, H1=2, H2=1
#define NNODES 50000
#define NEDGES 800000
#define NCHUNK ((NNODES + 255) / 256)   // 196

// ---- manual bf16 pack/unpack (no fp16/bf16 headers; plain uint words) ----
// pack two fp32 -> one uint (lo = a, hi = b), round-to-nearest-even
__device__ __forceinline__ unsigned bfpack(float a, float b) {
    unsigned ua = __float_as_uint(a), ub = __float_as_uint(b);
    ua = (ua + 0x7fffu + ((ua >> 16) & 1u)) >> 16;
    ub = (ub + 0x7fffu + ((ub >> 16) & 1u)) >> 16;
    return ua | (ub << 16);
}
__device__ __forceinline__ float bflo(unsigned u) { return __uint_as_float(u << 16); }
__device__ __forceinline__ float bfhi(unsigned u) { return __uint_as_float(u & 0xffff0000u); }

// ---------------- CSR build (by dst; shared by both layers) ----------------

__global__ __launch_bounds__(256) void hist_kernel(const int* __restrict__ dst,
                                                   int* __restrict__ deg) {
    int e = blockIdx.x * 256 + threadIdx.x;
    if (e < NEDGES) atomicAdd(&deg[dst[e]], 1);
}

__global__ __launch_bounds__(256) void scanA_kernel(const int* __restrict__ deg,
                                                    int* __restrict__ bsum) {
    __shared__ int s[256];
    int i = blockIdx.x * 256 + threadIdx.x;
    s[threadIdx.x] = (i < NNODES) ? deg[i] : 0;
    __syncthreads();
    for (int off = 128; off > 0; off >>= 1) {
        if (threadIdx.x < off) s[threadIdx.x] += s[threadIdx.x + off];
        __syncthreads();
    }
    if (threadIdx.x == 0) bsum[blockIdx.x] = s[0];
}

__global__ __launch_bounds__(64) void scanB_kernel(int* __restrict__ bsum) {
    int lane = threadIdx.x;
    int carry = 0;
    for (int base = 0; base < NCHUNK; base += 64) {
        int idx = base + lane;
        int v = (idx < NCHUNK) ? bsum[idx] : 0;
        int incl = v;
#pragma unroll
        for (int off = 1; off < 64; off <<= 1) {
            int t = __shfl_up(incl, off);
            if (lane >= off) incl += t;
        }
        if (idx < NCHUNK) bsum[idx] = carry + incl - v;  // exclusive
        carry += __shfl(incl, 63);
    }
}

__global__ __launch_bounds__(256) void scanC_kernel(const int* __restrict__ deg,
                                                    const int* __restrict__ bsum,
                                                    int* __restrict__ rowptr,
                                                    int* __restrict__ cursor) {
    __shared__ int s[256];
    int i = blockIdx.x * 256 + threadIdx.x;
    int v = (i < NNODES) ? deg[i] : 0;
    s[threadIdx.x] = v;
    __syncthreads();
    for (int off = 1; off < 256; off <<= 1) {
        int t = (threadIdx.x >= off) ? s[threadIdx.x - off] : 0;
        __syncthreads();
        s[threadIdx.x] += t;
        __syncthreads();
    }
    if (i < NNODES) {
        int excl = bsum[blockIdx.x] + s[threadIdx.x] - v;
        rowptr[i] = excl;
        cursor[i] = excl;
    }
}

__global__ __launch_bounds__(256) void fill_kernel(const int* __restrict__ src,
                                                   const int* __restrict__ dst,
                                                   int* __restrict__ cursor,
                                                   int* __restrict__ csr_src) {
    int e = blockIdx.x * 256 + threadIdx.x;
    if (e < NEDGES) {
        int pos = atomicAdd(&cursor[dst[e]], 1);
        csr_src[pos] = src[e];
    }
}

// ---------------- GEMMs: LDS-tiled, register-blocked fp32 -----------------
// Outputs h packed bf16 (gather format for aggregate); el/er in fp32.

// gemm1: h(N,128) = feat(N,128) @ W1(128,128), fused el/er.
// h stored as uint[ N ][ 64 ]: word j holds cols {2j, 2j+1}.
__global__ __launch_bounds__(256) void gemm1_kernel(
    const float* __restrict__ feat, const float* __restrict__ W,
    const float* __restrict__ al, const float* __restrict__ ar,
    unsigned* __restrict__ h, float* __restrict__ el, float* __restrict__ er) {
    __shared__ float As[64][36];      // pad 36: A-reads 2-way (free)
    __shared__ float Ws[32 * 128];
    const int tid = threadIdx.x;
    const int tx  = tid & 15;
    const int ty  = tid >> 4;
    const int n0  = blockIdx.x * 64;

    float acc[4][8];
#pragma unroll
    for (int i = 0; i < 4; ++i)
#pragma unroll
        for (int j = 0; j < 8; ++j) acc[i][j] = 0.f;

    for (int k0 = 0; k0 < 128; k0 += 32) {
#pragma unroll
        for (int i = 0; i < 2; ++i) {
            int fid = i * 256 + tid;
            int n = fid >> 3, j = fid & 7;
            float4 v = make_float4(0.f, 0.f, 0.f, 0.f);
            if (n0 + n < NNODES)
                v = *(const float4*)&feat[(size_t)(n0 + n) * 128 + k0 + 4 * j];
            *(float4*)&As[n][4 * j] = v;
        }
#pragma unroll
        for (int i = 0; i < 4; ++i) {
            int fid = i * 256 + tid;
            *(float4*)&Ws[fid * 4] = *(const float4*)&W[k0 * 128 + fid * 4];
        }
        __syncthreads();
#pragma unroll
        for (int k = 0; k < 32; ++k) {
            float a0 = As[ty * 4 + 0][k];
            float a1 = As[ty * 4 + 1][k];
            float a2 = As[ty * 4 + 2][k];
            float a3 = As[ty * 4 + 3][k];
            float4 w0 = *(const float4*)&Ws[k * 128 + tx * 4];
            float4 w1 = *(const float4*)&Ws[k * 128 + 64 + tx * 4];
            float wv[8] = {w0.x, w0.y, w0.z, w0.w, w1.x, w1.y, w1.z, w1.w};
#pragma unroll
            for (int j = 0; j < 8; ++j) {
                acc[0][j] = fmaf(a0, wv[j], acc[0][j]);
                acc[1][j] = fmaf(a1, wv[j], acc[1][j]);
                acc[2][j] = fmaf(a2, wv[j], acc[2][j]);
                acc[3][j] = fmaf(a3, wv[j], acc[3][j]);
            }
        }
        __syncthreads();
    }

    float alv[8], arv[8];
#pragma unroll
    for (int j = 0; j < 4; ++j) {
        alv[j]     = al[tx * 4 + j];        arv[j]     = ar[tx * 4 + j];
        alv[4 + j] = al[64 + tx * 4 + j];   arv[4 + j] = ar[64 + tx * 4 + j];
    }

#pragma unroll
    for (int i = 0; i < 4; ++i) {
        const int node = n0 + ty * 4 + i;
        if (node < NNODES) {
            uint2 o0 = {bfpack(acc[i][0], acc[i][1]), bfpack(acc[i][2], acc[i][3])};
            uint2 o1 = {bfpack(acc[i][4], acc[i][5]), bfpack(acc[i][6], acc[i][7])};
            *(uint2*)&h[(size_t)node * 64 + tx * 2]      = o0;  // cols tx*4..+3
            *(uint2*)&h[(size_t)node * 64 + 32 + tx * 2] = o1;  // cols 64+tx*4..+3
        }
        float vl0 = 0.f, vr0 = 0.f, vl1 = 0.f, vr1 = 0.f;
#pragma unroll
        for (int j = 0; j < 4; ++j) {
            vl0 = fmaf(acc[i][j], alv[j], vl0);
            vr0 = fmaf(acc[i][j], arv[j], vr0);
            vl1 = fmaf(acc[i][4 + j], alv[4 + j], vl1);
            vr1 = fmaf(acc[i][4 + j], arv[4 + j], vr1);
        }
#pragma unroll
        for (int m = 1; m <= 8; m <<= 1) {
            vl0 += __shfl_xor(vl0, m); vr0 += __shfl_xor(vr0, m);
            vl1 += __shfl_xor(vl1, m); vr1 += __shfl_xor(vr1, m);
        }
        if (tx == 0 && node < NNODES) {
            el[node * 2 + 0] = vl0;  er[node * 2 + 0] = vr0;
            el[node * 2 + 1] = vl1;  er[node * 2 + 1] = vr1;
        }
    }
}

// gemm2: h2(N,64) = h1(N,128) @ W2(128,64), fused el2/er2 (H=1).
// h2 stored as uint[ N ][ 32 ]: word j holds cols {2j, 2j+1}.
__global__ __launch_bounds__(256) void gemm2_kernel(
    const float* __restrict__ h1, const float* __restrict__ W,
    const float* __restrict__ al, const float* __restrict__ ar,
    unsigned* __restrict__ h2, float* __restrict__ el, float* __restrict__ er) {
    __shared__ float As[128][34];
    __shared__ float Ws[32 * 64];
    const int tid = threadIdx.x;
    const int tx  = tid & 15;
    const int ty  = tid >> 4;
    const int n0  = blockIdx.x * 128;

    float acc[8][4];
#pragma unroll
    for (int i = 0; i < 8; ++i)
#pragma unroll
        for (int j = 0; j < 4; ++j) acc[i][j] = 0.f;

    for (int k0 = 0; k0 < 128; k0 += 32) {
#pragma unroll
        for (int i = 0; i < 4; ++i) {
            int fid = i * 256 + tid;
            int n = fid >> 3, j = fid & 7;
            float4 v = make_float4(0.f, 0.f, 0.f, 0.f);
            if (n0 + n < NNODES)
                v = *(const float4*)&h1[(size_t)(n0 + n) * 128 + k0 + 4 * j];
            *(float2*)&As[n][4 * j]     = make_float2(v.x, v.y);
            *(float2*)&As[n][4 * j + 2] = make_float2(v.z, v.w);
        }
#pragma unroll
        for (int i = 0; i < 2; ++i) {
            int fid = i * 256 + tid;
            *(float4*)&Ws[fid * 4] = *(const float4*)&W[k0 * 64 + fid * 4];
        }
        __syncthreads();
#pragma unroll
        for (int k = 0; k < 32; ++k) {
            float4 w = *(const float4*)&Ws[k * 64 + tx * 4];
            float wv[4] = {w.x, w.y, w.z, w.w};
#pragma unroll
            for (int i = 0; i < 8; ++i) {
                float a = As[ty * 8 + i][k];
#pragma unroll
                for (int j = 0; j < 4; ++j)
                    acc[i][j] = fmaf(a, wv[j], acc[i][j]);
            }
        }
        __syncthreads();
    }

    float alv[4], arv[4];
#pragma unroll
    for (int j = 0; j < 4; ++j) { alv[j] = al[tx * 4 + j]; arv[j] = ar[tx * 4 + j]; }

#pragma unroll
    for (int i = 0; i < 8; ++i) {
        const int node = n0 + ty * 8 + i;
        if (node < NNODES) {
            uint2 o = {bfpack(acc[i][0], acc[i][1]), bfpack(acc[i][2], acc[i][3])};
            *(uint2*)&h2[(size_t)node * 32 + tx * 2] = o;
        }
        float vl = 0.f, vr = 0.f;
#pragma unroll
        for (int j = 0; j < 4; ++j) {
            vl = fmaf(acc[i][j], alv[j], vl);
            vr = fmaf(acc[i][j], arv[j], vr);
        }
#pragma unroll
        for (int m = 1; m <= 8; m <<= 1) {
            vl += __shfl_xor(vl, m); vr += __shfl_xor(vr, m);
        }
        if (tx == 0 && node < NNODES) { el[node] = vl; er[node] = vr; }
    }
}

// ---- layer-1 aggregate: ONE wave per node, BOTH heads per gather ----------
// h bf16-packed uint[node][64] (words 0-31 head0, 32-63 head1); lane j loads
// word j -> one 256B load/edge covers both heads. Softmax fp32 per head.
__global__ __launch_bounds__(256) void aggregate1_kernel(
    const int* __restrict__ rowptr, const int* __restrict__ degv,
    const int* __restrict__ csr_src,
    const float* __restrict__ el, const float* __restrict__ er,
    const unsigned* __restrict__ hh, const float* __restrict__ bias,
    float* __restrict__ outp) {
    const int node = (blockIdx.x * 256 + threadIdx.x) >> 6;
    const int lane = threadIdx.x & 63;
    if (node >= NNODES) return;
    const int row = rowptr[node];
    const int deg = degv[node];
    const float er0 = er[node * 2 + 0];
    const float er1 = er[node * 2 + 1];

    int   s_reg = 0;
    float v0 = -1e30f, v1 = -1e30f;
    if (lane < deg) {
        s_reg = csr_src[row + lane];
        float2 e = *(const float2*)&el[s_reg * 2];
        float a = e.x + er0; v0 = a > 0.f ? a : 0.2f * a;
        float b = e.y + er1; v1 = b > 0.f ? b : 0.2f * b;
    }
    float m0 = v0, m1 = v1;
    for (int i = 64 + lane; i < deg; i += 64) {          // rare (deg>64)
        int s = csr_src[row + i];
        float2 e = *(const float2*)&el[s * 2];
        float a = e.x + er0; a = a > 0.f ? a : 0.2f * a;
        float b = e.y + er1; b = b > 0.f ? b : 0.2f * b;
        m0 = fmaxf(m0, a); m1 = fmaxf(m1, b);
    }
#pragma unroll
    for (int off = 32; off > 0; off >>= 1) {
        m0 = fmaxf(m0, __shfl_xor(m0, off));
        m1 = fmaxf(m1, __shfl_xor(m1, off));
    }

    float p0 = (lane < deg) ? __expf(v0 - m0) : 0.f;
    float p1 = (lane < deg) ? __expf(v1 - m1) : 0.f;
    float ssum0 = p0, ssum1 = p1;
    for (int i = 64 + lane; i < deg; i += 64) {
        int s = csr_src[row + i];
        float2 e = *(const float2*)&el[s * 2];
        float a = e.x + er0; a = a > 0.f ? a : 0.2f * a;
        float b = e.y + er1; b = b > 0.f ? b : 0.2f * b;
        ssum0 += __expf(a - m0); ssum1 += __expf(b - m1);
    }
#pragma unroll
    for (int off = 32; off > 0; off >>= 1) {
        ssum0 += __shfl_xor(ssum0, off);
        ssum1 += __shfl_xor(ssum1, off);
    }

    const int head = lane >> 5;               // lane j -> cols {2j, 2j+1}
    float accx = 0.f, accy = 0.f;
    const int dmax = deg < 64 ? deg : 64;
    for (int i = 0; i < dmax; ++i) {
        int   s  = __shfl(s_reg, i);
        float a0 = __shfl(p0, i);
        float a1 = __shfl(p1, i);
        float alpha = head ? a1 : a0;
        unsigned hv = hh[(size_t)s * 64 + lane];
        accx = fmaf(alpha, bflo(hv), accx);
        accy = fmaf(alpha, bfhi(hv), accy);
    }
    for (int i = 64; i < deg; ++i) {          // rare
        int s = csr_src[row + i];
        float2 e = *(const float2*)&el[s * 2];
        float a = e.x + er0; a = a > 0.f ? a : 0.2f * a;
        float b = e.y + er1; b = b > 0.f ? b : 0.2f * b;
        float alpha = head ? __expf(b - m1) : __expf(a - m0);
        unsigned hv = hh[(size_t)s * 64 + lane];
        accx = fmaf(alpha, bflo(hv), accx);
        accy = fmaf(alpha, bfhi(hv), accy);
    }
    float ssum = head ? ssum1 : ssum0;
    if (deg > 0) { accx /= ssum; accy /= ssum; }

    float2 bb = *(const float2*)&bias[2 * lane];
    float o0 = accx + bb.x, o1 = accy + bb.y;
    o0 = o0 > 0.f ? o0 : (__expf(o0) - 1.f);
    o1 = o1 > 0.f ? o1 : (__expf(o1) - 1.f);
    *(float2*)&outp[(size_t)node * 128 + 2 * lane] = make_float2(o0, o1);
}

// ---- layer-2 aggregate: one wave per node; lanes 0-31 gather one word ----
__global__ __launch_bounds__(256) void aggregate2_kernel(
    const int* __restrict__ rowptr, const int* __restrict__ degv,
    const int* __restrict__ csr_src,
    const float* __restrict__ el, const float* __restrict__ er,
    const unsigned* __restrict__ hh, const float* __restrict__ bias,
    const float* __restrict__ h1, float* __restrict__ outp) {
    const int node = (blockIdx.x * 256 + threadIdx.x) >> 6;
    const int lane = threadIdx.x & 63;
    if (node >= NNODES) return;
    const int row = rowptr[node];
    const int deg = degv[node];
    const float erd = er[node];

    int   s_reg = 0;
    float v_reg = -1e30f;
    if (lane < deg) {
        s_reg = csr_src[row + lane];
        float v = el[s_reg] + erd;
        v_reg = v > 0.f ? v : 0.2f * v;
    }
    float m = v_reg;
    for (int i = 64 + lane; i < deg; i += 64) {
        int s = csr_src[row + i];
        float v = el[s] + erd;
        v = v > 0.f ? v : 0.2f * v;
        m = fmaxf(m, v);
    }
#pragma unroll
    for (int off = 32; off > 0; off >>= 1) m = fmaxf(m, __shfl_xor(m, off));

    float p_reg = (lane < deg) ? __expf(v_reg - m) : 0.f;
    float ssum = p_reg;
    for (int i = 64 + lane; i < deg; i += 64) {
        int s = csr_src[row + i];
        float v = el[s] + erd;
        v = v > 0.f ? v : 0.2f * v;
        ssum += __expf(v - m);
    }
#pragma unroll
    for (int off = 32; off > 0; off >>= 1) ssum += __shfl_xor(ssum, off);

    float accx = 0.f, accy = 0.f;
    const int dmax = deg < 64 ? deg : 64;
    for (int i = 0; i < dmax; ++i) {
        int   s = __shfl(s_reg, i);
        float p = __shfl(p_reg, i);
        if (lane < 32) {
            unsigned hv = hh[(size_t)s * 32 + lane];
            accx = fmaf(p, bflo(hv), accx);
            accy = fmaf(p, bfhi(hv), accy);
        }
    }
    for (int i = 64; i < deg; ++i) {          // rare
        int s = csr_src[row + i];
        float v = el[s] + erd;
        v = v > 0.f ? v : 0.2f * v;
        float p = __expf(v - m);
        if (lane < 32) {
            unsigned hv = hh[(size_t)s * 32 + lane];
            accx = fmaf(p, bflo(hv), accx);
            accy = fmaf(p, bfhi(hv), accy);
        }
    }
    if (lane < 32) {
        if (deg > 0) { accx /= ssum; accy /= ssum; }
        float2 hA = *(const float2*)&h1[(size_t)node * 128 + 2 * lane];
        float2 hB = *(const float2*)&h1[(size_t)node * 128 + 64 + 2 * lane];
        float2 bb = *(const float2*)&bias[2 * lane];
        float o0 = ((hA.x + hB.x) * 0.5f + accx + bb.x) * 0.5f;
        float o1 = ((hA.y + hB.y) * 0.5f + accy + bb.y) * 0.5f;
        *(float2*)&outp[(size_t)node * 64 + 2 * lane] = make_float2(o0, o1);
    }
}

// ---------------- launcher ----------------

extern "C" void kernel_launch(void* const* d_in, const int* in_sizes, int n_in,
                              void* d_out, int out_size, void* d_ws, size_t ws_size,
                              hipStream_t stream) {
    const float* feat = (const float*)d_in[0];
    const int*   src  = (const int*)d_in[1];
    const int*   dst  = (const int*)d_in[2];
    const float* W1   = (const float*)d_in[3];
    const float* al1  = (const float*)d_in[4];
    const float* ar1  = (const float*)d_in[5];
    const float* b1   = (const float*)d_in[6];
    const float* W2   = (const float*)d_in[7];
    const float* al2  = (const float*)d_in[8];
    const float* ar2  = (const float*)d_in[9];
    const float* b2   = (const float*)d_in[10];
    float* out = (float*)d_out;

    // workspace layout (4-byte units; ~50 MB total, 16B-aligned sections)
    int*      ideg  = (int*)d_ws;                        // N
    int*      irow  = ideg + NNODES;                     // N
    int*      icur  = irow + NNODES;                     // N
    int*      ibsum = icur + NNODES;                     // 256
    int*      icsr  = ibsum + 256;                       // E
    unsigned* fH1h  = (unsigned*)(icsr + NEDGES);        // N*64 uints (bf16x2)
    float*    fH1   = (float*)(fH1h + (size_t)NNODES * 64);  // N*128 fp32
    float*    fEl1  = fH1  + (size_t)NNODES * 128;       // N*2
    float*    fEr1  = fEl1 + (size_t)NNODES * 2;         // N*2
    unsigned* fH2h  = (unsigned*)(fEr1 + (size_t)NNODES * 2); // N*32 uints
    float*    fEl2  = (float*)(fH2h + (size_t)NNODES * 32);   // N
    float*    fEr2  = fEl2 + (size_t)NNODES;             // N

    // ---- CSR build (once; both layers share the graph) ----
    hipMemsetAsync(ideg, 0, NNODES * sizeof(int), stream);
    hist_kernel<<<(NEDGES + 255) / 256, 256, 0, stream>>>(dst, ideg);
    scanA_kernel<<<NCHUNK, 256, 0, stream>>>(ideg, ibsum);
    scanB_kernel<<<1, 64, 0, stream>>>(ibsum);
    scanC_kernel<<<NCHUNK, 256, 0, stream>>>(ideg, ibsum, irow, icur);
    fill_kernel<<<(NEDGES + 255) / 256, 256, 0, stream>>>(src, dst, icur, icsr);

    // ---- layer 1 ----
    gemm1_kernel<<<(NNODES + 63) / 64, 256, 0, stream>>>(feat, W1, al1, ar1,
                                                         fH1h, fEl1, fEr1);
    aggregate1_kernel<<<(NNODES + 3) / 4, 256, 0, stream>>>(
        irow, ideg, icsr, fEl1, fEr1, fH1h, b1, fH1);

    // ---- layer 2 ----
    gemm2_kernel<<<(NNODES + 127) / 128, 256, 0, stream>>>(fH1, W2, al2, ar2,
                                                           fH2h, fEl2, fEr2);
    aggregate2_kernel<<<(NNODES + 3) / 4, 256, 0, stream>>>(
        irow, ideg, icsr, fEl2, fEr2, fH2h, b2, fH1, out);
}

// Round 8
// 345.846 us; speedup vs baseline: 2.9243x; 1.0410x over previous
//
#include <hip/hip_runtime.h>
#include <math.h>

// Problem constants: N=50000, E=800000, IN=128, OUT=64, H1=2, H2=1
#define NNODES 50000
#define NEDGES 800000
#define NCHUNK ((NNODES + 255) / 256)   // 196

// ---- manual bf16 pack/unpack (plain uint words) ----
__device__ __forceinline__ unsigned bfpack(float a, float b) {
    unsigned ua = __float_as_uint(a), ub = __float_as_uint(b);
    ua = (ua + 0x7fffu + ((ua >> 16) & 1u)) >> 16;
    ub = (ub + 0x7fffu + ((ub >> 16) & 1u)) >> 16;
    return ua | (ub << 16);
}
__device__ __forceinline__ float bflo(unsigned u) { return __uint_as_float(u << 16); }
__device__ __forceinline__ float bfhi(unsigned u) { return __uint_as_float(u & 0xffff0000u); }

// ---------------- CSR build (by dst; shared by both layers) ----------------

__global__ __launch_bounds__(256) void hist_kernel(const int* __restrict__ dst,
                                                   int* __restrict__ deg) {
    int e = blockIdx.x * 256 + threadIdx.x;
    if (e < NEDGES) atomicAdd(&deg[dst[e]], 1);
}

__global__ __launch_bounds__(256) void scanA_kernel(const int* __restrict__ deg,
                                                    int* __restrict__ bsum) {
    __shared__ int s[256];
    int i = blockIdx.x * 256 + threadIdx.x;
    s[threadIdx.x] = (i < NNODES) ? deg[i] : 0;
    __syncthreads();
    for (int off = 128; off > 0; off >>= 1) {
        if (threadIdx.x < off) s[threadIdx.x] += s[threadIdx.x + off];
        __syncthreads();
    }
    if (threadIdx.x == 0) bsum[blockIdx.x] = s[0];
}

__global__ __launch_bounds__(64) void scanB_kernel(int* __restrict__ bsum) {
    int lane = threadIdx.x;
    int carry = 0;
    for (int base = 0; base < NCHUNK; base += 64) {
        int idx = base + lane;
        int v = (idx < NCHUNK) ? bsum[idx] : 0;
        int incl = v;
#pragma unroll
        for (int off = 1; off < 64; off <<= 1) {
            int t = __shfl_up(incl, off);
            if (lane >= off) incl += t;
        }
        if (idx < NCHUNK) bsum[idx] = carry + incl - v;  // exclusive
        carry += __shfl(incl, 63);
    }
}

__global__ __launch_bounds__(256) void scanC_kernel(const int* __restrict__ deg,
                                                    const int* __restrict__ bsum,
                                                    int* __restrict__ rowptr,
                                                    int* __restrict__ cursor) {
    __shared__ int s[256];
    int i = blockIdx.x * 256 + threadIdx.x;
    int v = (i < NNODES) ? deg[i] : 0;
    s[threadIdx.x] = v;
    __syncthreads();
    for (int off = 1; off < 256; off <<= 1) {
        int t = (threadIdx.x >= off) ? s[threadIdx.x - off] : 0;
        __syncthreads();
        s[threadIdx.x] += t;
        __syncthreads();
    }
    if (i < NNODES) {
        int excl = bsum[blockIdx.x] + s[threadIdx.x] - v;
        rowptr[i] = excl;
        cursor[i] = excl;
    }
}

__global__ __launch_bounds__(256) void fill_kernel(const int* __restrict__ src,
                                                   const int* __restrict__ dst,
                                                   int* __restrict__ cursor,
                                                   int* __restrict__ csr_src) {
    int e = blockIdx.x * 256 + threadIdx.x;
    if (e < NEDGES) {
        int pos = atomicAdd(&cursor[dst[e]], 1);
        csr_src[pos] = src[e];
    }
}

// ---------------- GEMMs: LDS-tiled, register-blocked fp32 -----------------

// gemm1: h(N,128) = feat(N,128) @ W1(128,128), fused el/er.
// h stored as uint[N][64]: word j holds cols {2j, 2j+1} (bf16x2).
__global__ __launch_bounds__(256) void gemm1_kernel(
    const float* __restrict__ feat, const float* __restrict__ W,
    const float* __restrict__ al, const float* __restrict__ ar,
    unsigned* __restrict__ h, float* __restrict__ el, float* __restrict__ er) {
    __shared__ float As[64][36];      // pad 36: A-reads 2-way (free)
    __shared__ float Ws[32 * 128];
    const int tid = threadIdx.x;
    const int tx  = tid & 15;
    const int ty  = tid >> 4;
    const int n0  = blockIdx.x * 64;

    float acc[4][8];
#pragma unroll
    for (int i = 0; i < 4; ++i)
#pragma unroll
        for (int j = 0; j < 8; ++j) acc[i][j] = 0.f;

    for (int k0 = 0; k0 < 128; k0 += 32) {
#pragma unroll
        for (int i = 0; i < 2; ++i) {
            int fid = i * 256 + tid;
            int n = fid >> 3, j = fid & 7;
            float4 v = make_float4(0.f, 0.f, 0.f, 0.f);
            if (n0 + n < NNODES)
                v = *(const float4*)&feat[(size_t)(n0 + n) * 128 + k0 + 4 * j];
            *(float4*)&As[n][4 * j] = v;
        }
#pragma unroll
        for (int i = 0; i < 4; ++i) {
            int fid = i * 256 + tid;
            *(float4*)&Ws[fid * 4] = *(const float4*)&W[k0 * 128 + fid * 4];
        }
        __syncthreads();
#pragma unroll
        for (int k = 0; k < 32; ++k) {
            float a0 = As[ty * 4 + 0][k];
            float a1 = As[ty * 4 + 1][k];
            float a2 = As[ty * 4 + 2][k];
            float a3 = As[ty * 4 + 3][k];
            float4 w0 = *(const float4*)&Ws[k * 128 + tx * 4];
            float4 w1 = *(const float4*)&Ws[k * 128 + 64 + tx * 4];
            float wv[8] = {w0.x, w0.y, w0.z, w0.w, w1.x, w1.y, w1.z, w1.w};
#pragma unroll
            for (int j = 0; j < 8; ++j) {
                acc[0][j] = fmaf(a0, wv[j], acc[0][j]);
                acc[1][j] = fmaf(a1, wv[j], acc[1][j]);
                acc[2][j] = fmaf(a2, wv[j], acc[2][j]);
                acc[3][j] = fmaf(a3, wv[j], acc[3][j]);
            }
        }
        __syncthreads();
    }

    float alv[8], arv[8];
#pragma unroll
    for (int j = 0; j < 4; ++j) {
        alv[j]     = al[tx * 4 + j];        arv[j]     = ar[tx * 4 + j];
        alv[4 + j] = al[64 + tx * 4 + j];   arv[4 + j] = ar[64 + tx * 4 + j];
    }

#pragma unroll
    for (int i = 0; i < 4; ++i) {
        const int node = n0 + ty * 4 + i;
        if (node < NNODES) {
            uint2 o0 = {bfpack(acc[i][0], acc[i][1]), bfpack(acc[i][2], acc[i][3])};
            uint2 o1 = {bfpack(acc[i][4], acc[i][5]), bfpack(acc[i][6], acc[i][7])};
            *(uint2*)&h[(size_t)node * 64 + tx * 2]      = o0;
            *(uint2*)&h[(size_t)node * 64 + 32 + tx * 2] = o1;
        }
        float vl0 = 0.f, vr0 = 0.f, vl1 = 0.f, vr1 = 0.f;
#pragma unroll
        for (int j = 0; j < 4; ++j) {
            vl0 = fmaf(acc[i][j], alv[j], vl0);
            vr0 = fmaf(acc[i][j], arv[j], vr0);
            vl1 = fmaf(acc[i][4 + j], alv[4 + j], vl1);
            vr1 = fmaf(acc[i][4 + j], arv[4 + j], vr1);
        }
#pragma unroll
        for (int m = 1; m <= 8; m <<= 1) {
            vl0 += __shfl_xor(vl0, m); vr0 += __shfl_xor(vr0, m);
            vl1 += __shfl_xor(vl1, m); vr1 += __shfl_xor(vr1, m);
        }
        if (tx == 0 && node < NNODES) {
            el[node * 2 + 0] = vl0;  er[node * 2 + 0] = vr0;
            el[node * 2 + 1] = vl1;  er[node * 2 + 1] = vr1;
        }
    }
}

// gemm2: h2(N,64) = h1(N,128) @ W2(128,64), fused el2/er2 (H=1).
// h2 stored as uint[N][32]: word j holds cols {2j, 2j+1}.
__global__ __launch_bounds__(256) void gemm2_kernel(
    const float* __restrict__ h1, const float* __restrict__ W,
    const float* __restrict__ al, const float* __restrict__ ar,
    unsigned* __restrict__ h2, float* __restrict__ el, float* __restrict__ er) {
    __shared__ float As[128][34];
    __shared__ float Ws[32 * 64];
    const int tid = threadIdx.x;
    const int tx  = tid & 15;
    const int ty  = tid >> 4;
    const int n0  = blockIdx.x * 128;

    float acc[8][4];
#pragma unroll
    for (int i = 0; i < 8; ++i)
#pragma unroll
        for (int j = 0; j < 4; ++j) acc[i][j] = 0.f;

    for (int k0 = 0; k0 < 128; k0 += 32) {
#pragma unroll
        for (int i = 0; i < 4; ++i) {
            int fid = i * 256 + tid;
            int n = fid >> 3, j = fid & 7;
            float4 v = make_float4(0.f, 0.f, 0.f, 0.f);
            if (n0 + n < NNODES)
                v = *(const float4*)&h1[(size_t)(n0 + n) * 128 + k0 + 4 * j];
            *(float2*)&As[n][4 * j]     = make_float2(v.x, v.y);
            *(float2*)&As[n][4 * j + 2] = make_float2(v.z, v.w);
        }
#pragma unroll
        for (int i = 0; i < 2; ++i) {
            int fid = i * 256 + tid;
            *(float4*)&Ws[fid * 4] = *(const float4*)&W[k0 * 64 + fid * 4];
        }
        __syncthreads();
#pragma unroll
        for (int k = 0; k < 32; ++k) {
            float4 w = *(const float4*)&Ws[k * 64 + tx * 4];
            float wv[4] = {w.x, w.y, w.z, w.w};
#pragma unroll
            for (int i = 0; i < 8; ++i) {
                float a = As[ty * 8 + i][k];
#pragma unroll
                for (int j = 0; j < 4; ++j)
                    acc[i][j] = fmaf(a, wv[j], acc[i][j]);
            }
        }
        __syncthreads();
    }

    float alv[4], arv[4];
#pragma unroll
    for (int j = 0; j < 4; ++j) { alv[j] = al[tx * 4 + j]; arv[j] = ar[tx * 4 + j]; }

#pragma unroll
    for (int i = 0; i < 8; ++i) {
        const int node = n0 + ty * 8 + i;
        if (node < NNODES) {
            uint2 o = {bfpack(acc[i][0], acc[i][1]), bfpack(acc[i][2], acc[i][3])};
            *(uint2*)&h2[(size_t)node * 32 + tx * 2] = o;
        }
        float vl = 0.f, vr = 0.f;
#pragma unroll
        for (int j = 0; j < 4; ++j) {
            vl = fmaf(acc[i][j], alv[j], vl);
            vr = fmaf(acc[i][j], arv[j], vr);
        }
#pragma unroll
        for (int m = 1; m <= 8; m <<= 1) {
            vl += __shfl_xor(vl, m); vr += __shfl_xor(vr, m);
        }
        if (tx == 0 && node < NNODES) { el[node] = vl; er[node] = vr; }
    }
}

// ---- layer-1 aggregate: ONE wave per node, BOTH heads per 256B gather -----
__global__ __launch_bounds__(256) void aggregate1_kernel(
    const int* __restrict__ rowptr, const int* __restrict__ degv,
    const int* __restrict__ csr_src,
    const float* __restrict__ el, const float* __restrict__ er,
    const unsigned* __restrict__ hh, const float* __restrict__ bias,
    float* __restrict__ outp) {
    const int node = (blockIdx.x * 256 + threadIdx.x) >> 6;
    const int lane = threadIdx.x & 63;
    if (node >= NNODES) return;
    const int row = rowptr[node];
    const int deg = degv[node];
    const float er0 = er[node * 2 + 0];
    const float er1 = er[node * 2 + 1];

    int   s_reg = 0;
    float v0 = -1e30f, v1 = -1e30f;
    if (lane < deg) {
        s_reg = csr_src[row + lane];
        float2 e = *(const float2*)&el[s_reg * 2];
        float a = e.x + er0; v0 = a > 0.f ? a : 0.2f * a;
        float b = e.y + er1; v1 = b > 0.f ? b : 0.2f * b;
    }
    float m0 = v0, m1 = v1;
    for (int i = 64 + lane; i < deg; i += 64) {          // rare (deg>64)
        int s = csr_src[row + i];
        float2 e = *(const float2*)&el[s * 2];
        float a = e.x + er0; a = a > 0.f ? a : 0.2f * a;
        float b = e.y + er1; b = b > 0.f ? b : 0.2f * b;
        m0 = fmaxf(m0, a); m1 = fmaxf(m1, b);
    }
#pragma unroll
    for (int off = 32; off > 0; off >>= 1) {
        m0 = fmaxf(m0, __shfl_xor(m0, off));
        m1 = fmaxf(m1, __shfl_xor(m1, off));
    }

    float p0 = (lane < deg) ? __expf(v0 - m0) : 0.f;
    float p1 = (lane < deg) ? __expf(v1 - m1) : 0.f;
    float ssum0 = p0, ssum1 = p1;
    for (int i = 64 + lane; i < deg; i += 64) {
        int s = csr_src[row + i];
        float2 e = *(const float2*)&el[s * 2];
        float a = e.x + er0; a = a > 0.f ? a : 0.2f * a;
        float b = e.y + er1; b = b > 0.f ? b : 0.2f * b;
        ssum0 += __expf(a - m0); ssum1 += __expf(b - m1);
    }
#pragma unroll
    for (int off = 32; off > 0; off >>= 1) {
        ssum0 += __shfl_xor(ssum0, off);
        ssum1 += __shfl_xor(ssum1, off);
    }

    const int head = lane >> 5;               // lane j -> cols {2j, 2j+1}
    float accx = 0.f, accy = 0.f;
    const int dmax = deg < 64 ? deg : 64;
    for (int i = 0; i < dmax; ++i) {
        int   s  = __shfl(s_reg, i);
        float a0 = __shfl(p0, i);
        float a1 = __shfl(p1, i);
        float alpha = head ? a1 : a0;
        unsigned hv = hh[(size_t)s * 64 + lane];
        accx = fmaf(alpha, bflo(hv), accx);
        accy = fmaf(alpha, bfhi(hv), accy);
    }
    for (int i = 64; i < deg; ++i) {          // rare
        int s = csr_src[row + i];
        float2 e = *(const float2*)&el[s * 2];
        float a = e.x + er0; a = a > 0.f ? a : 0.2f * a;
        float b = e.y + er1; b = b > 0.f ? b : 0.2f * b;
        float alpha = head ? __expf(b - m1) : __expf(a - m0);
        unsigned hv = hh[(size_t)s * 64 + lane];
        accx = fmaf(alpha, bflo(hv), accx);
        accy = fmaf(alpha, bfhi(hv), accy);
    }
    float ssum = head ? ssum1 : ssum0;
    if (deg > 0) { accx /= ssum; accy /= ssum; }

    float2 bb = *(const float2*)&bias[2 * lane];
    float o0 = accx + bb.x, o1 = accy + bb.y;
    o0 = o0 > 0.f ? o0 : (__expf(o0) - 1.f);
    o1 = o1 > 0.f ? o1 : (__expf(o1) - 1.f);
    *(float2*)&outp[(size_t)node * 128 + 2 * lane] = make_float2(o0, o1);
}

// ---- layer-2 aggregate: TWO nodes per wave (lanes 0-31 / 32-63) -----------
// All 64 lanes gather every iteration; 32-lane softmax per half.
// NNODES is even => both halves of a wave are valid or both exited (shuffle-safe).
__global__ __launch_bounds__(256) void aggregate2_kernel(
    const int* __restrict__ rowptr, const int* __restrict__ degv,
    const int* __restrict__ csr_src,
    const float* __restrict__ el, const float* __restrict__ er,
    const unsigned* __restrict__ hh, const float* __restrict__ bias,
    const float* __restrict__ h1, float* __restrict__ outp) {
    const int wid  = (blockIdx.x * 256 + threadIdx.x) >> 6;
    const int lane = threadIdx.x & 63;
    const int hl   = lane & 31;
    const int node = wid * 2 + (lane >> 5);
    if (node >= NNODES) return;
    const int row = rowptr[node];
    const int deg = degv[node];
    const float erd = er[node];

    int   s_reg = 0;
    float v_reg = -1e30f;
    if (hl < deg) {
        s_reg = csr_src[row + hl];
        float v = el[s_reg] + erd;
        v_reg = v > 0.f ? v : 0.2f * v;
    }
    float m = v_reg;
    for (int i = 32 + hl; i < deg; i += 32) {
        int s = csr_src[row + i];
        float v = el[s] + erd;
        v = v > 0.f ? v : 0.2f * v;
        m = fmaxf(m, v);
    }
#pragma unroll
    for (int off = 16; off > 0; off >>= 1) m = fmaxf(m, __shfl_xor(m, off));

    float p_reg = (hl < deg) ? __expf(v_reg - m) : 0.f;
    float ssum = p_reg;
    for (int i = 32 + hl; i < deg; i += 32) {
        int s = csr_src[row + i];
        float v = el[s] + erd;
        v = v > 0.f ? v : 0.2f * v;
        ssum += __expf(v - m);
    }
#pragma unroll
    for (int off = 16; off > 0; off >>= 1) ssum += __shfl_xor(ssum, off);

    float accx = 0.f, accy = 0.f;
    const int dmax = deg < 32 ? deg : 32;
    int dmW = dmax;
    dmW = max(dmW, __shfl_xor(dmW, 32));      // uniform wave loop bound
    for (int i = 0; i < dmW; ++i) {
        int   s = __shfl(s_reg, (lane & 32) + i);   // own half's edge i
        float p = __shfl(p_reg, (lane & 32) + i);
        if (i < dmax) {
            unsigned hv = hh[(size_t)s * 32 + hl];
            accx = fmaf(p, bflo(hv), accx);
            accy = fmaf(p, bfhi(hv), accy);
        }
    }
    for (int i = 32; i < deg; ++i) {          // rare per-half tail (deg>32)
        int s = csr_src[row + i];             // broadcast within half
        float v = el[s] + erd;
        v = v > 0.f ? v : 0.2f * v;
        float p = __expf(v - m);
        unsigned hv = hh[(size_t)s * 32 + hl];
        accx = fmaf(p, bflo(hv), accx);
        accy = fmaf(p, bfhi(hv), accy);
    }
    if (deg > 0) { accx /= ssum; accy /= ssum; }

    float2 hA = *(const float2*)&h1[(size_t)node * 128 + 2 * hl];
    float2 hB = *(const float2*)&h1[(size_t)node * 128 + 64 + 2 * hl];
    float2 bb = *(const float2*)&bias[2 * hl];
    float o0 = ((hA.x + hB.x) * 0.5f + accx + bb.x) * 0.5f;
    float o1 = ((hA.y + hB.y) * 0.5f + accy + bb.y) * 0.5f;
    *(float2*)&outp[(size_t)node * 64 + 2 * hl] = make_float2(o0, o1);
}

// ---------------- launcher ----------------

extern "C" void kernel_launch(void* const* d_in, const int* in_sizes, int n_in,
                              void* d_out, int out_size, void* d_ws, size_t ws_size,
                              hipStream_t stream) {
    const float* feat = (const float*)d_in[0];
    const int*   src  = (const int*)d_in[1];
    const int*   dst  = (const int*)d_in[2];
    const float* W1   = (const float*)d_in[3];
    const float* al1  = (const float*)d_in[4];
    const float* ar1  = (const float*)d_in[5];
    const float* b1   = (const float*)d_in[6];
    const float* W2   = (const float*)d_in[7];
    const float* al2  = (const float*)d_in[8];
    const float* ar2  = (const float*)d_in[9];
    const float* b2   = (const float*)d_in[10];
    float* out = (float*)d_out;

    // workspace layout (4-byte units; ~50 MB total, 16B-aligned sections)
    int*      ideg  = (int*)d_ws;                        // N
    int*      irow  = ideg + NNODES;                     // N
    int*      icur  = irow + NNODES;                     // N
    int*      ibsum = icur + NNODES;                     // 256
    int*      icsr  = ibsum + 256;                       // E
    unsigned* fH1h  = (unsigned*)(icsr + NEDGES);        // N*64 uints (bf16x2)
    float*    fH1   = (float*)(fH1h + (size_t)NNODES * 64);  // N*128 fp32
    float*    fEl1  = fH1  + (size_t)NNODES * 128;       // N*2
    float*    fEr1  = fEl1 + (size_t)NNODES * 2;         // N*2
    unsigned* fH2h  = (unsigned*)(fEr1 + (size_t)NNODES * 2); // N*32 uints
    float*    fEl2  = (float*)(fH2h + (size_t)NNODES * 32);   // N
    float*    fEr2  = fEl2 + (size_t)NNODES;             // N

    // ---- CSR build (once; both layers share the graph) ----
    hipMemsetAsync(ideg, 0, NNODES * sizeof(int), stream);
    hist_kernel<<<(NEDGES + 255) / 256, 256, 0, stream>>>(dst, ideg);
    scanA_kernel<<<NCHUNK, 256, 0, stream>>>(ideg, ibsum);
    scanB_kernel<<<1, 64, 0, stream>>>(ibsum);
    scanC_kernel<<<NCHUNK, 256, 0, stream>>>(ideg, ibsum, irow, icur);
    fill_kernel<<<(NEDGES + 255) / 256, 256, 0, stream>>>(src, dst, icur, icsr);

    // ---- layer 1 ----
    gemm1_kernel<<<(NNODES + 63) / 64, 256, 0, stream>>>(feat, W1, al1, ar1,
                                                         fH1h, fEl1, fEr1);
    aggregate1_kernel<<<(NNODES + 3) / 4, 256, 0, stream>>>(
        irow, ideg, icsr, fEl1, fEr1, fH1h, b1, fH1);

    // ---- layer 2 ----
    gemm2_kernel<<<(NNODES + 127) / 128, 256, 0, stream>>>(fH1, W2, al2, ar2,
                                                           fH2h, fEl2, fEr2);
    aggregate2_kernel<<<(NNODES / 2 + 3) / 4, 256, 0, stream>>>(
        irow, ideg, icsr, fEl2, fEr2, fH2h, b2, fH1, out);
}

// Round 11
// 332.160 us; speedup vs baseline: 3.0448x; 1.0412x over previous
//
#include <hip/hip_runtime.h>
#include <math.h>

// Problem constants: N=50000, E=800000, IN=128, OUT=64, H1=2, H2=1
#define NNODES 50000
#define NEDGES 800000
#define NCHUNK ((NNODES + 255) / 256)   // 196

// ---- manual bf16 pack/unpack (plain uint words) ----
__device__ __forceinline__ unsigned bfpack(float a, float b) {
    unsigned ua = __float_as_uint(a), ub = __float_as_uint(b);
    ua = (ua + 0x7fffu + ((ua >> 16) & 1u)) >> 16;
    ub = (ub + 0x7fffu + ((ub >> 16) & 1u)) >> 16;
    return ua | (ub << 16);
}
__device__ __forceinline__ float bflo(unsigned u) { return __uint_as_float(u << 16); }
__device__ __forceinline__ float bfhi(unsigned u) { return __uint_as_float(u & 0xffff0000u); }

// ---------------- CSR build (by dst; shared by both layers) ----------------

__global__ __launch_bounds__(256) void hist_kernel(const int* __restrict__ dst,
                                                   int* __restrict__ deg) {
    int e = blockIdx.x * 256 + threadIdx.x;
    if (e < NEDGES) atomicAdd(&deg[dst[e]], 1);
}

__global__ __launch_bounds__(256) void scanA_kernel(const int* __restrict__ deg,
                                                    int* __restrict__ bsum) {
    __shared__ int s[256];
    int i = blockIdx.x * 256 + threadIdx.x;
    s[threadIdx.x] = (i < NNODES) ? deg[i] : 0;
    __syncthreads();
    for (int off = 128; off > 0; off >>= 1) {
        if (threadIdx.x < off) s[threadIdx.x] += s[threadIdx.x + off];
        __syncthreads();
    }
    if (threadIdx.x == 0) bsum[blockIdx.x] = s[0];
}

__global__ __launch_bounds__(64) void scanB_kernel(int* __restrict__ bsum) {
    int lane = threadIdx.x;
    int carry = 0;
    for (int base = 0; base < NCHUNK; base += 64) {
        int idx = base + lane;
        int v = (idx < NCHUNK) ? bsum[idx] : 0;
        int incl = v;
#pragma unroll
        for (int off = 1; off < 64; off <<= 1) {
            int t = __shfl_up(incl, off);
            if (lane >= off) incl += t;
        }
        if (idx < NCHUNK) bsum[idx] = carry + incl - v;  // exclusive
        carry += __shfl(incl, 63);
    }
}

__global__ __launch_bounds__(256) void scanC_kernel(const int* __restrict__ deg,
                                                    const int* __restrict__ bsum,
                                                    int* __restrict__ rowptr,
                                                    int* __restrict__ cursor) {
    __shared__ int s[256];
    int i = blockIdx.x * 256 + threadIdx.x;
    int v = (i < NNODES) ? deg[i] : 0;
    s[threadIdx.x] = v;
    __syncthreads();
    for (int off = 1; off < 256; off <<= 1) {
        int t = (threadIdx.x >= off) ? s[threadIdx.x - off] : 0;
        __syncthreads();
        s[threadIdx.x] += t;
        __syncthreads();
    }
    if (i < NNODES) {
        int excl = bsum[blockIdx.x] + s[threadIdx.x] - v;
        rowptr[i] = excl;
        cursor[i] = excl;
    }
}

__global__ __launch_bounds__(256) void fill_kernel(const int* __restrict__ src,
                                                   const int* __restrict__ dst,
                                                   int* __restrict__ cursor,
                                                   int* __restrict__ csr_src) {
    int e = blockIdx.x * 256 + threadIdx.x;
    if (e < NEDGES) {
        int pos = atomicAdd(&cursor[dst[e]], 1);
        csr_src[pos] = src[e];
    }
}

// ---------------- GEMMs: LDS-tiled, register-blocked fp32 -----------------

// gemm1: h(N,128) = feat(N,128) @ W1(128,128), fused el/er.
// h stored as uint[N][64]: word j holds cols {2j, 2j+1} (bf16x2).
__global__ __launch_bounds__(256) void gemm1_kernel(
    const float* __restrict__ feat, const float* __restrict__ W,
    const float* __restrict__ al, const float* __restrict__ ar,
    unsigned* __restrict__ h, float* __restrict__ el, float* __restrict__ er) {
    __shared__ float As[64][36];      // pad 36: A-reads 2-way (free)
    __shared__ float Ws[32 * 128];
    const int tid = threadIdx.x;
    const int tx  = tid & 15;
    const int ty  = tid >> 4;
    const int n0  = blockIdx.x * 64;

    float acc[4][8];
#pragma unroll
    for (int i = 0; i < 4; ++i)
#pragma unroll
        for (int j = 0; j < 8; ++j) acc[i][j] = 0.f;

    for (int k0 = 0; k0 < 128; k0 += 32) {
#pragma unroll
        for (int i = 0; i < 2; ++i) {
            int fid = i * 256 + tid;
            int n = fid >> 3, j = fid & 7;
            float4 v = make_float4(0.f, 0.f, 0.f, 0.f);
            if (n0 + n < NNODES)
                v = *(const float4*)&feat[(size_t)(n0 + n) * 128 + k0 + 4 * j];
            *(float4*)&As[n][4 * j] = v;
        }
#pragma unroll
        for (int i = 0; i < 4; ++i) {
            int fid = i * 256 + tid;
            *(float4*)&Ws[fid * 4] = *(const float4*)&W[k0 * 128 + fid * 4];
        }
        __syncthreads();
#pragma unroll
        for (int k = 0; k < 32; ++k) {
            float a0 = As[ty * 4 + 0][k];
            float a1 = As[ty * 4 + 1][k];
            float a2 = As[ty * 4 + 2][k];
            float a3 = As[ty * 4 + 3][k];
            float4 w0 = *(const float4*)&Ws[k * 128 + tx * 4];
            float4 w1 = *(const float4*)&Ws[k * 128 + 64 + tx * 4];
            float wv[8] = {w0.x, w0.y, w0.z, w0.w, w1.x, w1.y, w1.z, w1.w};
#pragma unroll
            for (int j = 0; j < 8; ++j) {
                acc[0][j] = fmaf(a0, wv[j], acc[0][j]);
                acc[1][j] = fmaf(a1, wv[j], acc[1][j]);
                acc[2][j] = fmaf(a2, wv[j], acc[2][j]);
                acc[3][j] = fmaf(a3, wv[j], acc[3][j]);
            }
        }
        __syncthreads();
    }

    float alv[8], arv[8];
#pragma unroll
    for (int j = 0; j < 4; ++j) {
        alv[j]     = al[tx * 4 + j];        arv[j]     = ar[tx * 4 + j];
        alv[4 + j] = al[64 + tx * 4 + j];   arv[4 + j] = ar[64 + tx * 4 + j];
    }

#pragma unroll
    for (int i = 0; i < 4; ++i) {
        const int node = n0 + ty * 4 + i;
        if (node < NNODES) {
            uint2 o0 = {bfpack(acc[i][0], acc[i][1]), bfpack(acc[i][2], acc[i][3])};
            uint2 o1 = {bfpack(acc[i][4], acc[i][5]), bfpack(acc[i][6], acc[i][7])};
            *(uint2*)&h[(size_t)node * 64 + tx * 2]      = o0;
            *(uint2*)&h[(size_t)node * 64 + 32 + tx * 2] = o1;
        }
        float vl0 = 0.f, vr0 = 0.f, vl1 = 0.f, vr1 = 0.f;
#pragma unroll
        for (int j = 0; j < 4; ++j) {
            vl0 = fmaf(acc[i][j], alv[j], vl0);
            vr0 = fmaf(acc[i][j], arv[j], vr0);
            vl1 = fmaf(acc[i][4 + j], alv[4 + j], vl1);
            vr1 = fmaf(acc[i][4 + j], arv[4 + j], vr1);
        }
#pragma unroll
        for (int m = 1; m <= 8; m <<= 1) {
            vl0 += __shfl_xor(vl0, m); vr0 += __shfl_xor(vr0, m);
            vl1 += __shfl_xor(vl1, m); vr1 += __shfl_xor(vr1, m);
        }
        if (tx == 0 && node < NNODES) {
            el[node * 2 + 0] = vl0;  er[node * 2 + 0] = vr0;
            el[node * 2 + 1] = vl1;  er[node * 2 + 1] = vr1;
        }
    }
}

// gemm2: h2(N,64) = h1(N,128) @ W2(128,64), fused el2/er2 (H=1).
// h2 stored as uint[N][32]: word j holds cols {2j, 2j+1}.
__global__ __launch_bounds__(256) void gemm2_kernel(
    const float* __restrict__ h1, const float* __restrict__ W,
    const float* __restrict__ al, const float* __restrict__ ar,
    unsigned* __restrict__ h2, float* __restrict__ el, float* __restrict__ er) {
    __shared__ float As[128][34];
    __shared__ float Ws[32 * 64];
    const int tid = threadIdx.x;
    const int tx  = tid & 15;
    const int ty  = tid >> 4;
    const int n0  = blockIdx.x * 128;

    float acc[8][4];
#pragma unroll
    for (int i = 0; i < 8; ++i)
#pragma unroll
        for (int j = 0; j < 4; ++j) acc[i][j] = 0.f;

    for (int k0 = 0; k0 < 128; k0 += 32) {
#pragma unroll
        for (int i = 0; i < 4; ++i) {
            int fid = i * 256 + tid;
            int n = fid >> 3, j = fid & 7;
            float4 v = make_float4(0.f, 0.f, 0.f, 0.f);
            if (n0 + n < NNODES)
                v = *(const float4*)&h1[(size_t)(n0 + n) * 128 + k0 + 4 * j];
            *(float2*)&As[n][4 * j]     = make_float2(v.x, v.y);
            *(float2*)&As[n][4 * j + 2] = make_float2(v.z, v.w);
        }
#pragma unroll
        for (int i = 0; i < 2; ++i) {
            int fid = i * 256 + tid;
            *(float4*)&Ws[fid * 4] = *(const float4*)&W[k0 * 64 + fid * 4];
        }
        __syncthreads();
#pragma unroll
        for (int k = 0; k < 32; ++k) {
            float4 w = *(const float4*)&Ws[k * 64 + tx * 4];
            float wv[4] = {w.x, w.y, w.z, w.w};
#pragma unroll
            for (int i = 0; i < 8; ++i) {
                float a = As[ty * 8 + i][k];
#pragma unroll
                for (int j = 0; j < 4; ++j)
                    acc[i][j] = fmaf(a, wv[j], acc[i][j]);
            }
        }
        __syncthreads();
    }

    float alv[4], arv[4];
#pragma unroll
    for (int j = 0; j < 4; ++j) { alv[j] = al[tx * 4 + j]; arv[j] = ar[tx * 4 + j]; }

#pragma unroll
    for (int i = 0; i < 8; ++i) {
        const int node = n0 + ty * 8 + i;
        if (node < NNODES) {
            uint2 o = {bfpack(acc[i][0], acc[i][1]), bfpack(acc[i][2], acc[i][3])};
            *(uint2*)&h2[(size_t)node * 32 + tx * 2] = o;
        }
        float vl = 0.f, vr = 0.f;
#pragma unroll
        for (int j = 0; j < 4; ++j) {
            vl = fmaf(acc[i][j], alv[j], vl);
            vr = fmaf(acc[i][j], arv[j], vr);
        }
#pragma unroll
        for (int m = 1; m <= 8; m <<= 1) {
            vl += __shfl_xor(vl, m); vr += __shfl_xor(vr, m);
        }
        if (tx == 0 && node < NNODES) { el[node] = vl; er[node] = vr; }
    }
}

// ---- layer-1 aggregate: ONE wave per node, TWO edges per gather iter ------
// Softmax phase identical to R8 (64-lane, proven). Gather: lanes 0-31 take
// edge 2i, lanes 32-63 take edge 2i+1; lane hl loads uint2 = cols 4hl..4hl+3
// of its edge's row. Cross-half __shfl_xor(.,32) combine merges the two
// partial sums (same node, same cols). hl<16 -> head0, hl>=16 -> head1.
__global__ __launch_bounds__(256) void aggregate1_kernel(
    const int* __restrict__ rowptr, const int* __restrict__ degv,
    const int* __restrict__ csr_src,
    const float* __restrict__ el, const float* __restrict__ er,
    const unsigned* __restrict__ hh, const float* __restrict__ bias,
    float* __restrict__ outp) {
    const int node = (blockIdx.x * 256 + threadIdx.x) >> 6;
    const int lane = threadIdx.x & 63;
    if (node >= NNODES) return;
    const int row = rowptr[node];
    const int deg = degv[node];
    const float er0 = er[node * 2 + 0];
    const float er1 = er[node * 2 + 1];

    // ---- edge scores + softmax stats (identical structure to R8) ----
    int   s_reg = 0;
    float v0 = -1e30f, v1 = -1e30f;
    if (lane < deg) {
        s_reg = csr_src[row + lane];
        float2 e = *(const float2*)&el[s_reg * 2];
        float a = e.x + er0; v0 = a > 0.f ? a : 0.2f * a;
        float b = e.y + er1; v1 = b > 0.f ? b : 0.2f * b;
    }
    float m0 = v0, m1 = v1;
    for (int i = 64 + lane; i < deg; i += 64) {          // rare (deg>64)
        int s = csr_src[row + i];
        float2 e = *(const float2*)&el[s * 2];
        float a = e.x + er0; a = a > 0.f ? a : 0.2f * a;
        float b = e.y + er1; b = b > 0.f ? b : 0.2f * b;
        m0 = fmaxf(m0, a); m1 = fmaxf(m1, b);
    }
#pragma unroll
    for (int off = 32; off > 0; off >>= 1) {
        m0 = fmaxf(m0, __shfl_xor(m0, off));
        m1 = fmaxf(m1, __shfl_xor(m1, off));
    }

    float p0 = (lane < deg) ? __expf(v0 - m0) : 0.f;
    float p1 = (lane < deg) ? __expf(v1 - m1) : 0.f;
    float ssum0 = p0, ssum1 = p1;
    for (int i = 64 + lane; i < deg; i += 64) {
        int s = csr_src[row + i];
        float2 e = *(const float2*)&el[s * 2];
        float a = e.x + er0; a = a > 0.f ? a : 0.2f * a;
        float b = e.y + er1; b = b > 0.f ? b : 0.2f * b;
        ssum0 += __expf(a - m0); ssum1 += __expf(b - m1);
    }
#pragma unroll
    for (int off = 32; off > 0; off >>= 1) {
        ssum0 += __shfl_xor(ssum0, off);
        ssum1 += __shfl_xor(ssum1, off);
    }

    // ---- gather: two edges per iteration (one per half-wave) ----
    const int  half  = lane >> 5;             // 0 -> edge 2i, 1 -> edge 2i+1
    const int  hl    = lane & 31;             // col group: 4hl..4hl+3
    const bool h1sel = (hl >= 16);            // this lane's cols are head1
    float ax = 0.f, ay = 0.f, az = 0.f, aw = 0.f;
    const int dmax = deg < 64 ? deg : 64;
    for (int i = 0; i < dmax; i += 2) {
        int eidx = i + half;
        int esafe = eidx & 63;                // mask for shuffle safety
        int   s  = __shfl(s_reg, esafe);
        float a0 = __shfl(p0, esafe);
        float a1 = __shfl(p1, esafe);
        if (eidx < dmax) {
            float alpha = h1sel ? a1 : a0;
            uint2 hv = *(const uint2*)&hh[(size_t)s * 64 + 2 * hl];
            ax = fmaf(alpha, bflo(hv.x), ax);
            ay = fmaf(alpha, bfhi(hv.x), ay);
            az = fmaf(alpha, bflo(hv.y), az);
            aw = fmaf(alpha, bfhi(hv.y), aw);
        }
    }
    for (int i = 64; i < deg; i += 2) {       // rare tail (deg>64)
        int eidx = i + half;
        if (eidx < deg) {
            int s = csr_src[row + eidx];      // broadcast within half
            float2 e = *(const float2*)&el[s * 2];
            float a = e.x + er0; a = a > 0.f ? a : 0.2f * a;
            float b = e.y + er1; b = b > 0.f ? b : 0.2f * b;
            float alpha = h1sel ? __expf(b - m1) : __expf(a - m0);
            uint2 hv = *(const uint2*)&hh[(size_t)s * 64 + 2 * hl];
            ax = fmaf(alpha, bflo(hv.x), ax);
            ay = fmaf(alpha, bfhi(hv.x), ay);
            az = fmaf(alpha, bflo(hv.y), az);
            aw = fmaf(alpha, bfhi(hv.y), aw);
        }
    }
    // combine the two halves (both accumulated the same node's cols)
    ax += __shfl_xor(ax, 32);  ay += __shfl_xor(ay, 32);
    az += __shfl_xor(az, 32);  aw += __shfl_xor(aw, 32);

    float ssum = h1sel ? ssum1 : ssum0;
    if (deg > 0) { ax /= ssum; ay /= ssum; az /= ssum; aw /= ssum; }

    if (lane < 32) {
        float2 b0 = *(const float2*)&bias[4 * hl];
        float2 b1 = *(const float2*)&bias[4 * hl + 2];
        float o0 = ax + b0.x, o1 = ay + b0.y, o2 = az + b1.x, o3 = aw + b1.y;
        o0 = o0 > 0.f ? o0 : (__expf(o0) - 1.f);
        o1 = o1 > 0.f ? o1 : (__expf(o1) - 1.f);
        o2 = o2 > 0.f ? o2 : (__expf(o2) - 1.f);
        o3 = o3 > 0.f ? o3 : (__expf(o3) - 1.f);
        *(float2*)&outp[(size_t)node * 128 + 4 * hl]     = make_float2(o0, o1);
        *(float2*)&outp[(size_t)node * 128 + 4 * hl + 2] = make_float2(o2, o3);
    }
}

// ---- layer-2 aggregate: TWO nodes per wave (lanes 0-31 / 32-63) -----------
// Unchanged from R8 (proven).
__global__ __launch_bounds__(256) void aggregate2_kernel(
    const int* __restrict__ rowptr, const int* __restrict__ degv,
    const int* __restrict__ csr_src,
    const float* __restrict__ el, const float* __restrict__ er,
    const unsigned* __restrict__ hh, const float* __restrict__ bias,
    const float* __restrict__ h1, float* __restrict__ outp) {
    const int wid  = (blockIdx.x * 256 + threadIdx.x) >> 6;
    const int lane = threadIdx.x & 63;
    const int hl   = lane & 31;
    const int node = wid * 2 + (lane >> 5);
    if (node >= NNODES) return;
    const int row = rowptr[node];
    const int deg = degv[node];
    const float erd = er[node];

    int   s_reg = 0;
    float v_reg = -1e30f;
    if (hl < deg) {
        s_reg = csr_src[row + hl];
        float v = el[s_reg] + erd;
        v_reg = v > 0.f ? v : 0.2f * v;
    }
    float m = v_reg;
    for (int i = 32 + hl; i < deg; i += 32) {
        int s = csr_src[row + i];
        float v = el[s] + erd;
        v = v > 0.f ? v : 0.2f * v;
        m = fmaxf(m, v);
    }
#pragma unroll
    for (int off = 16; off > 0; off >>= 1) m = fmaxf(m, __shfl_xor(m, off));

    float p_reg = (hl < deg) ? __expf(v_reg - m) : 0.f;
    float ssum = p_reg;
    for (int i = 32 + hl; i < deg; i += 32) {
        int s = csr_src[row + i];
        float v = el[s] + erd;
        v = v > 0.f ? v : 0.2f * v;
        ssum += __expf(v - m);
    }
#pragma unroll
    for (int off = 16; off > 0; off >>= 1) ssum += __shfl_xor(ssum, off);

    float accx = 0.f, accy = 0.f;
    const int dmax = deg < 32 ? deg : 32;
    int dmW = dmax;
    dmW = max(dmW, __shfl_xor(dmW, 32));      // uniform wave loop bound
    for (int i = 0; i < dmW; ++i) {
        int   s = __shfl(s_reg, (lane & 32) + i);   // own half's edge i
        float p = __shfl(p_reg, (lane & 32) + i);
        if (i < dmax) {
            unsigned hv = hh[(size_t)s * 32 + hl];
            accx = fmaf(p, bflo(hv), accx);
            accy = fmaf(p, bfhi(hv), accy);
        }
    }
    for (int i = 32; i < deg; ++i) {          // rare per-half tail (deg>32)
        int s = csr_src[row + i];             // broadcast within half
        float v = el[s] + erd;
        v = v > 0.f ? v : 0.2f * v;
        float p = __expf(v - m);
        unsigned hv = hh[(size_t)s * 32 + hl];
        accx = fmaf(p, bflo(hv), accx);
        accy = fmaf(p, bfhi(hv), accy);
    }
    if (deg > 0) { accx /= ssum; accy /= ssum; }

    float2 hA = *(const float2*)&h1[(size_t)node * 128 + 2 * hl];
    float2 hB = *(const float2*)&h1[(size_t)node * 128 + 64 + 2 * hl];
    float2 bb = *(const float2*)&bias[2 * hl];
    float o0 = ((hA.x + hB.x) * 0.5f + accx + bb.x) * 0.5f;
    float o1 = ((hA.y + hB.y) * 0.5f + accy + bb.y) * 0.5f;
    *(float2*)&outp[(size_t)node * 64 + 2 * hl] = make_float2(o0, o1);
}

// ---------------- launcher ----------------

extern "C" void kernel_launch(void* const* d_in, const int* in_sizes, int n_in,
                              void* d_out, int out_size, void* d_ws, size_t ws_size,
                              hipStream_t stream) {
    const float* feat = (const float*)d_in[0];
    const int*   src  = (const int*)d_in[1];
    const int*   dst  = (const int*)d_in[2];
    const float* W1   = (const float*)d_in[3];
    const float* al1  = (const float*)d_in[4];
    const float* ar1  = (const float*)d_in[5];
    const float* b1   = (const float*)d_in[6];
    const float* W2   = (const float*)d_in[7];
    const float* al2  = (const float*)d_in[8];
    const float* ar2  = (const float*)d_in[9];
    const float* b2   = (const float*)d_in[10];
    float* out = (float*)d_out;

    // workspace layout (4-byte units; ~50 MB total, 16B-aligned sections)
    int*      ideg  = (int*)d_ws;                        // N
    int*      irow  = ideg + NNODES;                     // N
    int*      icur  = irow + NNODES;                     // N
    int*      ibsum = icur + NNODES;                     // 256
    int*      icsr  = ibsum + 256;                       // E
    unsigned* fH1h  = (unsigned*)(icsr + NEDGES);        // N*64 uints (bf16x2)
    float*    fH1   = (float*)(fH1h + (size_t)NNODES * 64);  // N*128 fp32
    float*    fEl1  = fH1  + (size_t)NNODES * 128;       // N*2
    float*    fEr1  = fEl1 + (size_t)NNODES * 2;         // N*2
    unsigned* fH2h  = (unsigned*)(fEr1 + (size_t)NNODES * 2); // N*32 uints
    float*    fEl2  = (float*)(fH2h + (size_t)NNODES * 32);   // N
    float*    fEr2  = fEl2 + (size_t)NNODES;             // N

    // ---- CSR build (once; both layers share the graph) ----
    hipMemsetAsync(ideg, 0, NNODES * sizeof(int), stream);
    hist_kernel<<<(NEDGES + 255) / 256, 256, 0, stream>>>(dst, ideg);
    scanA_kernel<<<NCHUNK, 256, 0, stream>>>(ideg, ibsum);
    scanB_kernel<<<1, 64, 0, stream>>>(ibsum);
    scanC_kernel<<<NCHUNK, 256, 0, stream>>>(ideg, ibsum, irow, icur);
    fill_kernel<<<(NEDGES + 255) / 256, 256, 0, stream>>>(src, dst, icur, icsr);

    // ---- layer 1 ----
    gemm1_kernel<<<(NNODES + 63) / 64, 256, 0, stream>>>(feat, W1, al1, ar1,
                                                         fH1h, fEl1, fEr1);
    aggregate1_kernel<<<(NNODES + 3) / 4, 256, 0, stream>>>(
        irow, ideg, icsr, fEl1, fEr1, fH1h, b1, fH1);

    // ---- layer 2 ----
    gemm2_kernel<<<(NNODES + 127) / 128, 256, 0, stream>>>(fH1, W2, al2, ar2,
                                                           fH2h, fEl2, fEr2);
    aggregate2_kernel<<<(NNODES / 2 + 3) / 4, 256, 0, stream>>>(
        irow, ideg, icsr, fEl2, fEr2, fH2h, b2, fH1, out);
}

// Round 12
// 320.383 us; speedup vs baseline: 3.1567x; 1.0368x over previous
//
#include <hip/hip_runtime.h>
#include <math.h>

// Problem constants: N=50000, E=800000, IN=128, OUT=64, H1=2, H2=1
#define NNODES 50000
#define NEDGES 800000

// ---- manual bf16 pack/unpack (plain uint words) ----
__device__ __forceinline__ unsigned bfpack(float a, float b) {
    unsigned ua = __float_as_uint(a), ub = __float_as_uint(b);
    ua = (ua + 0x7fffu + ((ua >> 16) & 1u)) >> 16;
    ub = (ub + 0x7fffu + ((ub >> 16) & 1u)) >> 16;
    return ua | (ub << 16);
}
__device__ __forceinline__ float bflo(unsigned u) { return __uint_as_float(u << 16); }
__device__ __forceinline__ float bfhi(unsigned u) { return __uint_as_float(u & 0xffff0000u); }

// ---------------- CSR build (by dst; shared by both layers) ----------------

__global__ __launch_bounds__(256) void hist_kernel(const int* __restrict__ dst,
                                                   int* __restrict__ deg) {
    int e = blockIdx.x * 256 + threadIdx.x;
    if (e < NEDGES) atomicAdd(&deg[dst[e]], 1);
}

// row allocation WITHOUT global scan: wave-local shfl scan + 1 atomic/wave.
// Row order != node order (harmless: each row is still contiguous).
__global__ __launch_bounds__(256) void alloc_kernel(const int* __restrict__ deg,
                                                    int* __restrict__ total,
                                                    int* __restrict__ rowptr,
                                                    int* __restrict__ cursor) {
    const int i = blockIdx.x * 256 + threadIdx.x;
    const int lane = threadIdx.x & 63;
    int d = (i < NNODES) ? deg[i] : 0;
    int incl = d;
#pragma unroll
    for (int off = 1; off < 64; off <<= 1) {
        int t = __shfl_up(incl, off);
        if (lane >= off) incl += t;
    }
    int base = 0;
    if (lane == 63) base = atomicAdd(total, incl);   // incl@63 == wave total
    base = __shfl(base, 63);
    if (i < NNODES) {
        int pos = base + incl - d;                   // exclusive within wave
        rowptr[i] = pos;
        cursor[i] = pos;
    }
}

__global__ __launch_bounds__(256) void fill_kernel(const int* __restrict__ src,
                                                   const int* __restrict__ dst,
                                                   int* __restrict__ cursor,
                                                   int* __restrict__ csr_src) {
    int e = blockIdx.x * 256 + threadIdx.x;
    if (e < NEDGES) {
        int pos = atomicAdd(&cursor[dst[e]], 1);
        csr_src[pos] = src[e];
    }
}

// ---------------- GEMMs: LDS-tiled, register-blocked fp32 -----------------

// gemm1: h(N,128) = feat(N,128) @ W1(128,128), fused el/er.
// h stored as uint[N][64]: word j holds cols {2j, 2j+1} (bf16x2).
__global__ __launch_bounds__(256) void gemm1_kernel(
    const float* __restrict__ feat, const float* __restrict__ W,
    const float* __restrict__ al, const float* __restrict__ ar,
    unsigned* __restrict__ h, float* __restrict__ el, float* __restrict__ er) {
    __shared__ float As[64][36];      // pad 36: A-reads 2-way (free)
    __shared__ float Ws[32 * 128];
    const int tid = threadIdx.x;
    const int tx  = tid & 15;
    const int ty  = tid >> 4;
    const int n0  = blockIdx.x * 64;

    float acc[4][8];
#pragma unroll
    for (int i = 0; i < 4; ++i)
#pragma unroll
        for (int j = 0; j < 8; ++j) acc[i][j] = 0.f;

    for (int k0 = 0; k0 < 128; k0 += 32) {
#pragma unroll
        for (int i = 0; i < 2; ++i) {
            int fid = i * 256 + tid;
            int n = fid >> 3, j = fid & 7;
            float4 v = make_float4(0.f, 0.f, 0.f, 0.f);
            if (n0 + n < NNODES)
                v = *(const float4*)&feat[(size_t)(n0 + n) * 128 + k0 + 4 * j];
            *(float4*)&As[n][4 * j] = v;
        }
#pragma unroll
        for (int i = 0; i < 4; ++i) {
            int fid = i * 256 + tid;
            *(float4*)&Ws[fid * 4] = *(const float4*)&W[k0 * 128 + fid * 4];
        }
        __syncthreads();
#pragma unroll
        for (int k = 0; k < 32; ++k) {
            float a0 = As[ty * 4 + 0][k];
            float a1 = As[ty * 4 + 1][k];
            float a2 = As[ty * 4 + 2][k];
            float a3 = As[ty * 4 + 3][k];
            float4 w0 = *(const float4*)&Ws[k * 128 + tx * 4];
            float4 w1 = *(const float4*)&Ws[k * 128 + 64 + tx * 4];
            float wv[8] = {w0.x, w0.y, w0.z, w0.w, w1.x, w1.y, w1.z, w1.w};
#pragma unroll
            for (int j = 0; j < 8; ++j) {
                acc[0][j] = fmaf(a0, wv[j], acc[0][j]);
                acc[1][j] = fmaf(a1, wv[j], acc[1][j]);
                acc[2][j] = fmaf(a2, wv[j], acc[2][j]);
                acc[3][j] = fmaf(a3, wv[j], acc[3][j]);
            }
        }
        __syncthreads();
    }

    float alv[8], arv[8];
#pragma unroll
    for (int j = 0; j < 4; ++j) {
        alv[j]     = al[tx * 4 + j];        arv[j]     = ar[tx * 4 + j];
        alv[4 + j] = al[64 + tx * 4 + j];   arv[4 + j] = ar[64 + tx * 4 + j];
    }

#pragma unroll
    for (int i = 0; i < 4; ++i) {
        const int node = n0 + ty * 4 + i;
        if (node < NNODES) {
            uint2 o0 = {bfpack(acc[i][0], acc[i][1]), bfpack(acc[i][2], acc[i][3])};
            uint2 o1 = {bfpack(acc[i][4], acc[i][5]), bfpack(acc[i][6], acc[i][7])};
            *(uint2*)&h[(size_t)node * 64 + tx * 2]      = o0;
            *(uint2*)&h[(size_t)node * 64 + 32 + tx * 2] = o1;
        }
        float vl0 = 0.f, vr0 = 0.f, vl1 = 0.f, vr1 = 0.f;
#pragma unroll
        for (int j = 0; j < 4; ++j) {
            vl0 = fmaf(acc[i][j], alv[j], vl0);
            vr0 = fmaf(acc[i][j], arv[j], vr0);
            vl1 = fmaf(acc[i][4 + j], alv[4 + j], vl1);
            vr1 = fmaf(acc[i][4 + j], arv[4 + j], vr1);
        }
#pragma unroll
        for (int m = 1; m <= 8; m <<= 1) {
            vl0 += __shfl_xor(vl0, m); vr0 += __shfl_xor(vr0, m);
            vl1 += __shfl_xor(vl1, m); vr1 += __shfl_xor(vr1, m);
        }
        if (tx == 0 && node < NNODES) {
            el[node * 2 + 0] = vl0;  er[node * 2 + 0] = vr0;
            el[node * 2 + 1] = vl1;  er[node * 2 + 1] = vr1;
        }
    }
}

// gemm2: h2(N,64) = h1(N,128) @ W2(128,64), fused el2/er2 (H=1).
// h2 stored as uint[N][32]: word j holds cols {2j, 2j+1}.
__global__ __launch_bounds__(256) void gemm2_kernel(
    const float* __restrict__ h1, const float* __restrict__ W,
    const float* __restrict__ al, const float* __restrict__ ar,
    unsigned* __restrict__ h2, float* __restrict__ el, float* __restrict__ er) {
    __shared__ float As[128][34];
    __shared__ float Ws[32 * 64];
    const int tid = threadIdx.x;
    const int tx  = tid & 15;
    const int ty  = tid >> 4;
    const int n0  = blockIdx.x * 128;

    float acc[8][4];
#pragma unroll
    for (int i = 0; i < 8; ++i)
#pragma unroll
        for (int j = 0; j < 4; ++j) acc[i][j] = 0.f;

    for (int k0 = 0; k0 < 128; k0 += 32) {
#pragma unroll
        for (int i = 0; i < 4; ++i) {
            int fid = i * 256 + tid;
            int n = fid >> 3, j = fid & 7;
            float4 v = make_float4(0.f, 0.f, 0.f, 0.f);
            if (n0 + n < NNODES)
                v = *(const float4*)&h1[(size_t)(n0 + n) * 128 + k0 + 4 * j];
            *(float2*)&As[n][4 * j]     = make_float2(v.x, v.y);
            *(float2*)&As[n][4 * j + 2] = make_float2(v.z, v.w);
        }
#pragma unroll
        for (int i = 0; i < 2; ++i) {
            int fid = i * 256 + tid;
            *(float4*)&Ws[fid * 4] = *(const float4*)&W[k0 * 64 + fid * 4];
        }
        __syncthreads();
#pragma unroll
        for (int k = 0; k < 32; ++k) {
            float4 w = *(const float4*)&Ws[k * 64 + tx * 4];
            float wv[4] = {w.x, w.y, w.z, w.w};
#pragma unroll
            for (int i = 0; i < 8; ++i) {
                float a = As[ty * 8 + i][k];
#pragma unroll
                for (int j = 0; j < 4; ++j)
                    acc[i][j] = fmaf(a, wv[j], acc[i][j]);
            }
        }
        __syncthreads();
    }

    float alv[4], arv[4];
#pragma unroll
    for (int j = 0; j < 4; ++j) { alv[j] = al[tx * 4 + j]; arv[j] = ar[tx * 4 + j]; }

#pragma unroll
    for (int i = 0; i < 8; ++i) {
        const int node = n0 + ty * 8 + i;
        if (node < NNODES) {
            uint2 o = {bfpack(acc[i][0], acc[i][1]), bfpack(acc[i][2], acc[i][3])};
            *(uint2*)&h2[(size_t)node * 32 + tx * 2] = o;
        }
        float vl = 0.f, vr = 0.f;
#pragma unroll
        for (int j = 0; j < 4; ++j) {
            vl = fmaf(acc[i][j], alv[j], vl);
            vr = fmaf(acc[i][j], arv[j], vr);
        }
#pragma unroll
        for (int m = 1; m <= 8; m <<= 1) {
            vl += __shfl_xor(vl, m); vr += __shfl_xor(vr, m);
        }
        if (tx == 0 && node < NNODES) { el[node] = vl; er[node] = vr; }
    }
}

// ---- layer-1 aggregate: ONE wave per node, FOUR edges per gather iter -----
// Softmax phase identical to R8/R11 (64-lane, proven). Gather: quarter
// q=lane>>4 takes edge i+q; lane ql=lane&15 loads uint4 = cols 8ql..8ql+7
// (16 lanes x 16B = 256B row). Combine: shfl_xor 16 then 32.
__global__ __launch_bounds__(256) void aggregate1_kernel(
    const int* __restrict__ rowptr, const int* __restrict__ degv,
    const int* __restrict__ csr_src,
    const float* __restrict__ el, const float* __restrict__ er,
    const unsigned* __restrict__ hh, const float* __restrict__ bias,
    float* __restrict__ outp) {
    const int node = (blockIdx.x * 256 + threadIdx.x) >> 6;
    const int lane = threadIdx.x & 63;
    if (node >= NNODES) return;
    const int row = rowptr[node];
    const int deg = degv[node];
    const float er0 = er[node * 2 + 0];
    const float er1 = er[node * 2 + 1];

    // ---- edge scores + softmax stats (64-lane, proven structure) ----
    int   s_reg = 0;
    float v0 = -1e30f, v1 = -1e30f;
    if (lane < deg) {
        s_reg = csr_src[row + lane];
        float2 e = *(const float2*)&el[s_reg * 2];
        float a = e.x + er0; v0 = a > 0.f ? a : 0.2f * a;
        float b = e.y + er1; v1 = b > 0.f ? b : 0.2f * b;
    }
    float m0 = v0, m1 = v1;
    for (int i = 64 + lane; i < deg; i += 64) {          // rare (deg>64)
        int s = csr_src[row + i];
        float2 e = *(const float2*)&el[s * 2];
        float a = e.x + er0; a = a > 0.f ? a : 0.2f * a;
        float b = e.y + er1; b = b > 0.f ? b : 0.2f * b;
        m0 = fmaxf(m0, a); m1 = fmaxf(m1, b);
    }
#pragma unroll
    for (int off = 32; off > 0; off >>= 1) {
        m0 = fmaxf(m0, __shfl_xor(m0, off));
        m1 = fmaxf(m1, __shfl_xor(m1, off));
    }

    float p0 = (lane < deg) ? __expf(v0 - m0) : 0.f;
    float p1 = (lane < deg) ? __expf(v1 - m1) : 0.f;
    float ssum0 = p0, ssum1 = p1;
    for (int i = 64 + lane; i < deg; i += 64) {
        int s = csr_src[row + i];
        float2 e = *(const float2*)&el[s * 2];
        float a = e.x + er0; a = a > 0.f ? a : 0.2f * a;
        float b = e.y + er1; b = b > 0.f ? b : 0.2f * b;
        ssum0 += __expf(a - m0); ssum1 += __expf(b - m1);
    }
#pragma unroll
    for (int off = 32; off > 0; off >>= 1) {
        ssum0 += __shfl_xor(ssum0, off);
        ssum1 += __shfl_xor(ssum1, off);
    }

    // ---- gather: four edges per iteration (one per quarter-wave) ----
    const int  q     = lane >> 4;             // quarter: edge i+q
    const int  ql    = lane & 15;             // col group: 8ql..8ql+7
    const bool h1sel = (ql >= 8);             // cols 64.. are head1
    float a0r = 0.f, a1r = 0.f, a2r = 0.f, a3r = 0.f;
    float a4r = 0.f, a5r = 0.f, a6r = 0.f, a7r = 0.f;
    const int dmax = deg < 64 ? deg : 64;
    for (int i = 0; i < dmax; i += 4) {
        int eidx = i + q;
        int esafe = eidx & 63;                // mask for shuffle safety
        int   s  = __shfl(s_reg, esafe);
        float p0s = __shfl(p0, esafe);
        float p1s = __shfl(p1, esafe);
        if (eidx < dmax) {
            float alpha = h1sel ? p1s : p0s;
            uint4 hv = *(const uint4*)&hh[(size_t)s * 64 + 4 * ql];
            a0r = fmaf(alpha, bflo(hv.x), a0r);
            a1r = fmaf(alpha, bfhi(hv.x), a1r);
            a2r = fmaf(alpha, bflo(hv.y), a2r);
            a3r = fmaf(alpha, bfhi(hv.y), a3r);
            a4r = fmaf(alpha, bflo(hv.z), a4r);
            a5r = fmaf(alpha, bfhi(hv.z), a5r);
            a6r = fmaf(alpha, bflo(hv.w), a6r);
            a7r = fmaf(alpha, bfhi(hv.w), a7r);
        }
    }
    for (int i = 64; i < deg; i += 4) {       // rare tail (deg>64)
        int eidx = i + q;
        if (eidx < deg) {
            int s = csr_src[row + eidx];
            float2 e = *(const float2*)&el[s * 2];
            float a = e.x + er0; a = a > 0.f ? a : 0.2f * a;
            float b = e.y + er1; b = b > 0.f ? b : 0.2f * b;
            float alpha = h1sel ? __expf(b - m1) : __expf(a - m0);
            uint4 hv = *(const uint4*)&hh[(size_t)s * 64 + 4 * ql];
            a0r = fmaf(alpha, bflo(hv.x), a0r);
            a1r = fmaf(alpha, bfhi(hv.x), a1r);
            a2r = fmaf(alpha, bflo(hv.y), a2r);
            a3r = fmaf(alpha, bfhi(hv.y), a3r);
            a4r = fmaf(alpha, bflo(hv.z), a4r);
            a5r = fmaf(alpha, bfhi(hv.z), a5r);
            a6r = fmaf(alpha, bflo(hv.w), a6r);
            a7r = fmaf(alpha, bfhi(hv.w), a7r);
        }
    }
    // combine quarters (all four accumulated the same node's cols)
    a0r += __shfl_xor(a0r, 16);  a1r += __shfl_xor(a1r, 16);
    a2r += __shfl_xor(a2r, 16);  a3r += __shfl_xor(a3r, 16);
    a4r += __shfl_xor(a4r, 16);  a5r += __shfl_xor(a5r, 16);
    a6r += __shfl_xor(a6r, 16);  a7r += __shfl_xor(a7r, 16);
    a0r += __shfl_xor(a0r, 32);  a1r += __shfl_xor(a1r, 32);
    a2r += __shfl_xor(a2r, 32);  a3r += __shfl_xor(a3r, 32);
    a4r += __shfl_xor(a4r, 32);  a5r += __shfl_xor(a5r, 32);
    a6r += __shfl_xor(a6r, 32);  a7r += __shfl_xor(a7r, 32);

    if (lane < 16) {
        float ssum = h1sel ? ssum1 : ssum0;
        if (deg > 0) {
            float inv = 1.f / ssum;
            a0r *= inv; a1r *= inv; a2r *= inv; a3r *= inv;
            a4r *= inv; a5r *= inv; a6r *= inv; a7r *= inv;
        }
        float4 b0 = *(const float4*)&bias[8 * ql];
        float4 b1 = *(const float4*)&bias[8 * ql + 4];
        float o0 = a0r + b0.x, o1 = a1r + b0.y, o2 = a2r + b0.z, o3 = a3r + b0.w;
        float o4 = a4r + b1.x, o5 = a5r + b1.y, o6 = a6r + b1.z, o7 = a7r + b1.w;
        o0 = o0 > 0.f ? o0 : (__expf(o0) - 1.f);
        o1 = o1 > 0.f ? o1 : (__expf(o1) - 1.f);
        o2 = o2 > 0.f ? o2 : (__expf(o2) - 1.f);
        o3 = o3 > 0.f ? o3 : (__expf(o3) - 1.f);
        o4 = o4 > 0.f ? o4 : (__expf(o4) - 1.f);
        o5 = o5 > 0.f ? o5 : (__expf(o5) - 1.f);
        o6 = o6 > 0.f ? o6 : (__expf(o6) - 1.f);
        o7 = o7 > 0.f ? o7 : (__expf(o7) - 1.f);
        *(float4*)&outp[(size_t)node * 128 + 8 * ql]     = make_float4(o0, o1, o2, o3);
        *(float4*)&outp[(size_t)node * 128 + 8 * ql + 4] = make_float4(o4, o5, o6, o7);
    }
}

// ---- layer-2 aggregate: TWO nodes per wave, TWO edges per iter per node ---
// Halves = nodes (proven R8). Within a half: sub-half s2=(hl>>4) takes edge
// i+s2; lane sl=hl&15 loads uint2 = cols 4sl..4sl+3 (16 lanes x 8B = 128B).
// Combine: shfl_xor 16 (stays within the half).
__global__ __launch_bounds__(256) void aggregate2_kernel(
    const int* __restrict__ rowptr, const int* __restrict__ degv,
    const int* __restrict__ csr_src,
    const float* __restrict__ el, const float* __restrict__ er,
    const unsigned* __restrict__ hh, const float* __restrict__ bias,
    const float* __restrict__ h1, float* __restrict__ outp) {
    const int wid  = (blockIdx.x * 256 + threadIdx.x) >> 6;
    const int lane = threadIdx.x & 63;
    const int hl   = lane & 31;
    const int node = wid * 2 + (lane >> 5);
    if (node >= NNODES) return;
    const int row = rowptr[node];
    const int deg = degv[node];
    const float erd = er[node];

    int   s_reg = 0;
    float v_reg = -1e30f;
    if (hl < deg) {
        s_reg = csr_src[row + hl];
        float v = el[s_reg] + erd;
        v_reg = v > 0.f ? v : 0.2f * v;
    }
    float m = v_reg;
    for (int i = 32 + hl; i < deg; i += 32) {
        int s = csr_src[row + i];
        float v = el[s] + erd;
        v = v > 0.f ? v : 0.2f * v;
        m = fmaxf(m, v);
    }
#pragma unroll
    for (int off = 16; off > 0; off >>= 1) m = fmaxf(m, __shfl_xor(m, off));

    float p_reg = (hl < deg) ? __expf(v_reg - m) : 0.f;
    float ssum = p_reg;
    for (int i = 32 + hl; i < deg; i += 32) {
        int s = csr_src[row + i];
        float v = el[s] + erd;
        v = v > 0.f ? v : 0.2f * v;
        ssum += __expf(v - m);
    }
#pragma unroll
    for (int off = 16; off > 0; off >>= 1) ssum += __shfl_xor(ssum, off);

    const int s2 = hl >> 4;                   // sub-half: edge i+s2
    const int sl = hl & 15;                   // col group: 4sl..4sl+3
    float ax = 0.f, ay = 0.f, az = 0.f, aw = 0.f;
    const int dmax = deg < 32 ? deg : 32;
    int dmW = dmax;
    dmW = max(dmW, __shfl_xor(dmW, 32));      // uniform wave loop bound
    for (int i = 0; i < dmW; i += 2) {
        int eidx = i + s2;
        int esafe = (lane & 32) + (eidx & 31);     // own half's edge
        int   s = __shfl(s_reg, esafe);
        float p = __shfl(p_reg, esafe);
        if (eidx < dmax) {
            uint2 hv = *(const uint2*)&hh[(size_t)s * 32 + 2 * sl];
            ax = fmaf(p, bflo(hv.x), ax);
            ay = fmaf(p, bfhi(hv.x), ay);
            az = fmaf(p, bflo(hv.y), az);
            aw = fmaf(p, bfhi(hv.y), aw);
        }
    }
    for (int i = 32; i < deg; i += 2) {       // rare per-half tail (deg>32)
        int eidx = i + s2;
        if (eidx < deg) {
            int s = csr_src[row + eidx];
            float v = el[s] + erd;
            v = v > 0.f ? v : 0.2f * v;
            float p = __expf(v - m);
            uint2 hv = *(const uint2*)&hh[(size_t)s * 32 + 2 * sl];
            ax = fmaf(p, bflo(hv.x), ax);
            ay = fmaf(p, bfhi(hv.x), ay);
            az = fmaf(p, bflo(hv.y), az);
            aw = fmaf(p, bfhi(hv.y), aw);
        }
    }
    // combine sub-halves (xor 16 stays inside this node's half)
    ax += __shfl_xor(ax, 16);  ay += __shfl_xor(ay, 16);
    az += __shfl_xor(az, 16);  aw += __shfl_xor(aw, 16);

    if (sl == hl) {                           // lanes with s2==0 write
        if (deg > 0) {
            float inv = 1.f / ssum;
            ax *= inv; ay *= inv; az *= inv; aw *= inv;
        }
        float4 hA = *(const float4*)&h1[(size_t)node * 128 + 4 * sl];
        float4 hB = *(const float4*)&h1[(size_t)node * 128 + 64 + 4 * sl];
        float4 bb = *(const float4*)&bias[4 * sl];
        float o0 = ((hA.x + hB.x) * 0.5f + ax + bb.x) * 0.5f;
        float o1 = ((hA.y + hB.y) * 0.5f + ay + bb.y) * 0.5f;
        float o2 = ((hA.z + hB.z) * 0.5f + az + bb.z) * 0.5f;
        float o3 = ((hA.w + hB.w) * 0.5f + aw + bb.w) * 0.5f;
        *(float4*)&outp[(size_t)node * 64 + 4 * sl] = make_float4(o0, o1, o2, o3);
    }
}

// ---------------- launcher ----------------

extern "C" void kernel_launch(void* const* d_in, const int* in_sizes, int n_in,
                              void* d_out, int out_size, void* d_ws, size_t ws_size,
                              hipStream_t stream) {
    const float* feat = (const float*)d_in[0];
    const int*   src  = (const int*)d_in[1];
    const int*   dst  = (const int*)d_in[2];
    const float* W1   = (const float*)d_in[3];
    const float* al1  = (const float*)d_in[4];
    const float* ar1  = (const float*)d_in[5];
    const float* b1   = (const float*)d_in[6];
    const float* W2   = (const float*)d_in[7];
    const float* al2  = (const float*)d_in[8];
    const float* ar2  = (const float*)d_in[9];
    const float* b2   = (const float*)d_in[10];
    float* out = (float*)d_out;

    // workspace layout (4-byte units; ~50 MB total, 16B-aligned sections)
    int*      ideg  = (int*)d_ws;                        // N
    int*      itot  = ideg + NNODES;                     // 4 (global cursor)
    int*      irow  = itot + 4;                          // N
    int*      icur  = irow + NNODES;                     // N
    int*      icsr  = icur + NNODES;                     // E
    unsigned* fH1h  = (unsigned*)(icsr + NEDGES);        // N*64 uints (bf16x2)
    float*    fH1   = (float*)(fH1h + (size_t)NNODES * 64);  // N*128 fp32
    float*    fEl1  = fH1  + (size_t)NNODES * 128;       // N*2
    float*    fEr1  = fEl1 + (size_t)NNODES * 2;         // N*2
    unsigned* fH2h  = (unsigned*)(fEr1 + (size_t)NNODES * 2); // N*32 uints
    float*    fEl2  = (float*)(fH2h + (size_t)NNODES * 32);   // N
    float*    fEr2  = fEl2 + (size_t)NNODES;             // N

    // ---- CSR build: memset + hist + alloc + fill (4 dispatches) ----
    hipMemsetAsync(ideg, 0, (NNODES + 4) * sizeof(int), stream);  // deg + cursor
    hist_kernel<<<(NEDGES + 255) / 256, 256, 0, stream>>>(dst, ideg);
    alloc_kernel<<<(NNODES + 255) / 256, 256, 0, stream>>>(ideg, itot, irow, icur);
    fill_kernel<<<(NEDGES + 255) / 256, 256, 0, stream>>>(src, dst, icur, icsr);

    // ---- layer 1 ----
    gemm1_kernel<<<(NNODES + 63) / 64, 256, 0, stream>>>(feat, W1, al1, ar1,
                                                         fH1h, fEl1, fEr1);
    aggregate1_kernel<<<(NNODES + 3) / 4, 256, 0, stream>>>(
        irow, ideg, icsr, fEl1, fEr1, fH1h, b1, fH1);

    // ---- layer 2 ----
    gemm2_kernel<<<(NNODES + 127) / 128, 256, 0, stream>>>(fH1, W2, al2, ar2,
                                                           fH2h, fEl2, fEr2);
    aggregate2_kernel<<<(NNODES / 2 + 3) / 4, 256, 0, stream>>>(
        irow, ideg, icsr, fEl2, fEr2, fH2h, b2, fH1, out);
}